// Round 1
// baseline (883.938 us; speedup 1.0000x reference)
//
#include <hip/hip_runtime.h>
#include <hip/hip_bf16.h>
#include <math.h>

#define NNODES 50000
#define NEDGES 800000

// ---------------- CSR build (sort edges by dst) ----------------

__global__ __launch_bounds__(256) void hist_kernel(const int* __restrict__ dst,
                                                   int* __restrict__ counts, int ne) {
  int i = blockIdx.x * blockDim.x + threadIdx.x;
  if (i < ne) atomicAdd(&counts[dst[i]], 1);
}

// single block, 256 threads: exclusive scan of counts -> offsets[N+1], cursor[N]
__global__ __launch_bounds__(256) void exscan_kernel(const int* __restrict__ counts,
                                                     int* __restrict__ offsets,
                                                     int* __restrict__ cursor, int n) {
  const int T = 256;
  int tid = threadIdx.x;
  int chunk = (n + T - 1) / T;
  int begin = tid * chunk; if (begin > n) begin = n;
  int end = begin + chunk; if (end > n) end = n;
  int sum = 0;
  for (int i = begin; i < end; ++i) sum += counts[i];
  int lane = tid & 63, wid = tid >> 6;
  int v = sum;
  #pragma unroll
  for (int o = 1; o < 64; o <<= 1) {
    int u = __shfl_up(v, o, 64);
    if (lane >= o) v += u;
  }
  __shared__ int wsums[4];
  if (lane == 63) wsums[wid] = v;
  __syncthreads();
  if (tid == 0) {
    int a = 0;
    for (int w = 0; w < 4; ++w) { int t = wsums[w]; wsums[w] = a; a += t; }
  }
  __syncthreads();
  int run = wsums[wid] + (v - sum);   // exclusive prefix for this thread's segment
  for (int i = begin; i < end; ++i) {
    int c = counts[i];
    offsets[i] = run;
    cursor[i] = run;
    run += c;
  }
  if (tid == T - 1) offsets[n] = run;
}

__global__ __launch_bounds__(256) void scatter_kernel(const int* __restrict__ dst,
                                                      int* __restrict__ cursor,
                                                      int* __restrict__ perm, int ne) {
  int i = blockIdx.x * blockDim.x + threadIdx.x;
  if (i < ne) {
    int pos = atomicAdd(&cursor[dst[i]], 1);
    perm[pos] = i;
  }
}

// ---------------- fp32 tiled GEMM: C[M,D] = A[M,K] @ B[K,D] ----------------
// 64x64 tile, BK=16, 256 threads, 4x4 micro-tile. K % 16 == 0, D % 64 == 0.

__global__ __launch_bounds__(256) void gemm_kernel(const float* __restrict__ A,
                                                   const float* __restrict__ B,
                                                   float* __restrict__ C,
                                                   int M, int K, int D) {
  __shared__ float AsT[16][64];  // transposed A tile: [k][row]
  __shared__ float Bs[16][64];   // [k][col]
  int tid = threadIdx.x;
  int tx = tid & 15, ty = tid >> 4;
  int row0 = blockIdx.x * 64, col0 = blockIdx.y * 64;
  float acc[4][4] = {};

  int arow = tid >> 2;        // 0..63
  int acg  = (tid & 3) * 4;   // 0,4,8,12
  int brow = tid >> 4;        // 0..15
  int bcg  = (tid & 15) * 4;  // 0..60
  int grow = row0 + arow;

  for (int k0 = 0; k0 < K; k0 += 16) {
    float4 av;
    if (grow < M) av = *(const float4*)&A[(size_t)grow * K + k0 + acg];
    else          av = make_float4(0.f, 0.f, 0.f, 0.f);
    float4 bv = *(const float4*)&B[(size_t)(k0 + brow) * D + col0 + bcg];
    __syncthreads();
    AsT[acg + 0][arow] = av.x;
    AsT[acg + 1][arow] = av.y;
    AsT[acg + 2][arow] = av.z;
    AsT[acg + 3][arow] = av.w;
    *(float4*)&Bs[brow][bcg] = bv;
    __syncthreads();
    #pragma unroll
    for (int k = 0; k < 16; ++k) {
      float4 a4 = *(const float4*)&AsT[k][ty * 4];
      float4 b4 = *(const float4*)&Bs[k][tx * 4];
      float a[4] = {a4.x, a4.y, a4.z, a4.w};
      float b[4] = {b4.x, b4.y, b4.z, b4.w};
      #pragma unroll
      for (int i = 0; i < 4; ++i)
        #pragma unroll
        for (int j = 0; j < 4; ++j)
          acc[i][j] += a[i] * b[j];
    }
  }
  #pragma unroll
  for (int i = 0; i < 4; ++i) {
    int r = row0 + ty * 4 + i;
    if (r < M) {
      float4 o = make_float4(acc[i][0], acc[i][1], acc[i][2], acc[i][3]);
      *(float4*)&C[(size_t)r * D + col0 + tx * 4] = o;
    }
  }
}

// ---------------- per-node attention logits: als/ald [N,H] ----------------
// block = D = H*C threads, one node per block. a_src/a_dst flat [H*C].

template<int H, int C>
__global__ __launch_bounds__(128) void attnlog_kernel(const float* __restrict__ h,
                                                      const float* __restrict__ a_src,
                                                      const float* __restrict__ a_dst,
                                                      float* __restrict__ als,
                                                      float* __restrict__ ald, int n_nodes) {
  constexpr int D = H * C;
  int n = blockIdx.x;
  int t = threadIdx.x;
  float hv = h[(size_t)n * D + t];
  float s = hv * a_src[t];
  float d = hv * a_dst[t];
  #pragma unroll
  for (int o = C / 2; o > 0; o >>= 1) {
    s += __shfl_xor(s, o, C);
    d += __shfl_xor(d, o, C);
  }
  if ((t & (C - 1)) == 0) {
    als[n * H + t / C] = s;
    ald[n * H + t / C] = d;
  }
}

// ---------------- per-dst-node softmax + weighted aggregation ----------------
// one 64-lane wave per destination node. H==4,C==32 (D=128) or H==1,C==64.

template<int H, int C, bool RELU>
__global__ __launch_bounds__(256) void aggregate_kernel(const float* __restrict__ h,
                                                        const float* __restrict__ als,
                                                        const float* __restrict__ ald,
                                                        const float* __restrict__ ew,
                                                        const int* __restrict__ src,
                                                        const int* __restrict__ offsets,
                                                        const int* __restrict__ perm,
                                                        const float* __restrict__ bias,
                                                        float* __restrict__ out, int n_nodes) {
  constexpr int D = H * C;
  int node = blockIdx.x * (blockDim.x >> 6) + (threadIdx.x >> 6);
  int lane = threadIdx.x & 63;
  if (node >= n_nodes) return;
  int start = offsets[node], end = offsets[node + 1];

  if constexpr (H == 4) {
    float ald0 = ald[node * 4 + 0], ald1 = ald[node * 4 + 1];
    float ald2 = ald[node * 4 + 2], ald3 = ald[node * 4 + 3];
    // pass 1: lane-parallel max of leaky logits per head
    float m0 = -INFINITY, m1 = -INFINITY, m2 = -INFINITY, m3 = -INFINITY;
    for (int j = start + lane; j < end; j += 64) {
      int e = perm[j];
      int s = src[e];
      float4 a4 = *(const float4*)&als[s * 4];
      float v0 = a4.x + ald0; v0 = v0 > 0.f ? v0 : 0.2f * v0; m0 = fmaxf(m0, v0);
      float v1 = a4.y + ald1; v1 = v1 > 0.f ? v1 : 0.2f * v1; m1 = fmaxf(m1, v1);
      float v2 = a4.z + ald2; v2 = v2 > 0.f ? v2 : 0.2f * v2; m2 = fmaxf(m2, v2);
      float v3 = a4.w + ald3; v3 = v3 > 0.f ? v3 : 0.2f * v3; m3 = fmaxf(m3, v3);
    }
    #pragma unroll
    for (int o = 32; o > 0; o >>= 1) {
      m0 = fmaxf(m0, __shfl_xor(m0, o));
      m1 = fmaxf(m1, __shfl_xor(m1, o));
      m2 = fmaxf(m2, __shfl_xor(m2, o));
      m3 = fmaxf(m3, __shfl_xor(m3, o));
    }
    // pass 2: lane covers channels lane (heads 0/1) and lane+64 (heads 2/3)
    int sel = (lane >> 5) & 1;
    float aldA = sel ? ald1 : ald0;
    float aldB = sel ? ald3 : ald2;
    float mA = sel ? m1 : m0;
    float mB = sel ? m3 : m2;
    float accA = 0.f, accB = 0.f, dA = 0.f, dB = 0.f;
    for (int j = start; j < end; ++j) {
      int e = perm[j];
      int s = src[e];
      float wgt = ew[e];
      float vA = als[s * 4 + sel] + aldA;       vA = vA > 0.f ? vA : 0.2f * vA;
      float vB = als[s * 4 + 2 + sel] + aldB;   vB = vB > 0.f ? vB : 0.2f * vB;
      float wA = __expf(vA - mA) * wgt;
      float wB = __expf(vB - mB) * wgt;
      dA += wA; dB += wB;
      accA += wA * h[(size_t)s * 128 + lane];
      accB += wB * h[(size_t)s * 128 + 64 + lane];
    }
    float oA = accA / (dA + 1e-16f) + bias[lane];
    float oB = accB / (dB + 1e-16f) + bias[64 + lane];
    if (RELU) { oA = fmaxf(oA, 0.f); oB = fmaxf(oB, 0.f); }
    out[(size_t)node * 128 + lane] = oA;
    out[(size_t)node * 128 + 64 + lane] = oB;
  } else {
    // H == 1, C == 64
    float ald0 = ald[node];
    float m0 = -INFINITY;
    for (int j = start + lane; j < end; j += 64) {
      int e = perm[j];
      int s = src[e];
      float v = als[s] + ald0; v = v > 0.f ? v : 0.2f * v;
      m0 = fmaxf(m0, v);
    }
    #pragma unroll
    for (int o = 32; o > 0; o >>= 1) m0 = fmaxf(m0, __shfl_xor(m0, o));
    float acc = 0.f, dd = 0.f;
    for (int j = start; j < end; ++j) {
      int e = perm[j];
      int s = src[e];
      float wgt = ew[e];
      float v = als[s] + ald0; v = v > 0.f ? v : 0.2f * v;
      float w = __expf(v - m0) * wgt;
      dd += w;
      acc += w * h[(size_t)s * 64 + lane];
    }
    float o = acc / (dd + 1e-16f) + bias[lane];
    if (RELU) o = fmaxf(o, 0.f);
    out[(size_t)node * 64 + lane] = o;
  }
}

// ---------------- launch ----------------

extern "C" void kernel_launch(void* const* d_in, const int* in_sizes, int n_in,
                              void* d_out, int out_size, void* d_ws, size_t ws_size,
                              hipStream_t stream) {
  const int N = NNODES, E = NEDGES;
  const float* x   = (const float*)d_in[0];
  const int*   ei  = (const int*)d_in[1];
  const float* ew  = (const float*)d_in[2];
  const float* W1  = (const float*)d_in[3];
  const float* as1 = (const float*)d_in[4];
  const float* ad1 = (const float*)d_in[5];
  const float* b1  = (const float*)d_in[6];
  const float* W2  = (const float*)d_in[7];
  const float* as2 = (const float*)d_in[8];
  const float* ad2 = (const float*)d_in[9];
  const float* b2  = (const float*)d_in[10];
  const float* W3  = (const float*)d_in[11];
  const float* as3 = (const float*)d_in[12];
  const float* ad3 = (const float*)d_in[13];
  const float* b3  = (const float*)d_in[14];
  const int* src = ei;
  const int* dst = ei + E;

  uint8_t* p = (uint8_t*)d_ws;
  auto carve = [&](size_t bytes) {
    void* r = (void*)p;
    p += (bytes + 255) & ~(size_t)255;
    return r;
  };
  int*   counts  = (int*)carve((size_t)N * 4);
  int*   offsets = (int*)carve((size_t)(N + 1) * 4);
  int*   cursor  = (int*)carve((size_t)N * 4);
  int*   perm    = (int*)carve((size_t)E * 4);
  float* als     = (float*)carve((size_t)N * 4 * 4);
  float* ald     = (float*)carve((size_t)N * 4 * 4);
  float* hA      = (float*)carve((size_t)N * 128 * 4);
  float* hB      = (float*)carve((size_t)N * 128 * 4);

  // CSR by dst (edge list is identical every call but must be rebuilt in-launch)
  hipMemsetAsync(counts, 0, (size_t)N * 4, stream);
  hist_kernel<<<(E + 255) / 256, 256, 0, stream>>>(dst, counts, E);
  exscan_kernel<<<1, 256, 0, stream>>>(counts, offsets, cursor, N);
  scatter_kernel<<<(E + 255) / 256, 256, 0, stream>>>(dst, cursor, perm, E);

  int aggGrid = (N + 3) / 4;

  // layer 1: [N,256] @ [256,128], H=4 C=32, relu
  gemm_kernel<<<dim3((N + 63) / 64, 2), 256, 0, stream>>>(x, W1, hA, N, 256, 128);
  attnlog_kernel<4, 32><<<N, 128, 0, stream>>>(hA, as1, ad1, als, ald, N);
  aggregate_kernel<4, 32, true><<<aggGrid, 256, 0, stream>>>(hA, als, ald, ew, src, offsets,
                                                             perm, b1, hB, N);
  // layer 2: [N,128] @ [128,128], H=4 C=32, relu
  gemm_kernel<<<dim3((N + 63) / 64, 2), 256, 0, stream>>>(hB, W2, hA, N, 128, 128);
  attnlog_kernel<4, 32><<<N, 128, 0, stream>>>(hA, as2, ad2, als, ald, N);
  aggregate_kernel<4, 32, true><<<aggGrid, 256, 0, stream>>>(hA, als, ald, ew, src, offsets,
                                                             perm, b2, hB, N);
  // layer 3: [N,128] @ [128,64], H=1 C=64, no relu, output fp32
  gemm_kernel<<<dim3((N + 63) / 64, 1), 256, 0, stream>>>(hB, W3, hA, N, 128, 64);
  attnlog_kernel<1, 64><<<N, 64, 0, stream>>>(hA, as3, ad3, als, ald, N);
  aggregate_kernel<1, 64, false><<<aggGrid, 256, 0, stream>>>(hA, als, ald, ew, src, offsets,
                                                              perm, b3, (float*)d_out, N);
}

// Round 2
// 683.776 us; speedup vs baseline: 1.2927x; 1.2927x over previous
//
#include <hip/hip_runtime.h>
#include <hip/hip_bf16.h>
#include <math.h>

#define NNODES 50000
#define NEDGES 800000

// ---------------- CSR build (sort edges by dst) ----------------

__global__ __launch_bounds__(256) void hist_kernel(const int* __restrict__ dst,
                                                   int* __restrict__ counts, int ne) {
  int i = blockIdx.x * blockDim.x + threadIdx.x;
  if (i < ne) atomicAdd(&counts[dst[i]], 1);
}

// single block, 256 threads: exclusive scan of counts -> offsets[N+1], cursor[N]
__global__ __launch_bounds__(256) void exscan_kernel(const int* __restrict__ counts,
                                                     int* __restrict__ offsets,
                                                     int* __restrict__ cursor, int n) {
  const int T = 256;
  int tid = threadIdx.x;
  int chunk = (n + T - 1) / T;
  int begin = tid * chunk; if (begin > n) begin = n;
  int end = begin + chunk; if (end > n) end = n;
  int sum = 0;
  for (int i = begin; i < end; ++i) sum += counts[i];
  int lane = tid & 63, wid = tid >> 6;
  int v = sum;
  #pragma unroll
  for (int o = 1; o < 64; o <<= 1) {
    int u = __shfl_up(v, o, 64);
    if (lane >= o) v += u;
  }
  __shared__ int wsums[4];
  if (lane == 63) wsums[wid] = v;
  __syncthreads();
  if (tid == 0) {
    int a = 0;
    for (int w = 0; w < 4; ++w) { int t = wsums[w]; wsums[w] = a; a += t; }
  }
  __syncthreads();
  int run = wsums[wid] + (v - sum);   // exclusive prefix for this thread's segment
  for (int i = begin; i < end; ++i) {
    int c = counts[i];
    offsets[i] = run;
    cursor[i] = run;
    run += c;
  }
  if (tid == T - 1) offsets[n] = run;
}

__global__ __launch_bounds__(256) void scatter_kernel(const int* __restrict__ dst,
                                                      int* __restrict__ cursor,
                                                      int* __restrict__ perm, int ne) {
  int i = blockIdx.x * blockDim.x + threadIdx.x;
  if (i < ne) {
    int pos = atomicAdd(&cursor[dst[i]], 1);
    perm[pos] = i;
  }
}

// ---------------- fp32 tiled GEMM: C[M,D] = A[M,K] @ B[K,D] ----------------
// 64x64 tile, BK=16, 256 threads, 4x4 micro-tile. K % 16 == 0, D % 64 == 0.

__global__ __launch_bounds__(256) void gemm_kernel(const float* __restrict__ A,
                                                   const float* __restrict__ B,
                                                   float* __restrict__ C,
                                                   int M, int K, int D) {
  __shared__ float AsT[16][64];  // transposed A tile: [k][row]
  __shared__ float Bs[16][64];   // [k][col]
  int tid = threadIdx.x;
  int tx = tid & 15, ty = tid >> 4;
  int row0 = blockIdx.x * 64, col0 = blockIdx.y * 64;
  float acc[4][4] = {};

  int arow = tid >> 2;        // 0..63
  int acg  = (tid & 3) * 4;   // 0,4,8,12
  int brow = tid >> 4;        // 0..15
  int bcg  = (tid & 15) * 4;  // 0..60
  int grow = row0 + arow;

  for (int k0 = 0; k0 < K; k0 += 16) {
    float4 av;
    if (grow < M) av = *(const float4*)&A[(size_t)grow * K + k0 + acg];
    else          av = make_float4(0.f, 0.f, 0.f, 0.f);
    float4 bv = *(const float4*)&B[(size_t)(k0 + brow) * D + col0 + bcg];
    __syncthreads();
    AsT[acg + 0][arow] = av.x;
    AsT[acg + 1][arow] = av.y;
    AsT[acg + 2][arow] = av.z;
    AsT[acg + 3][arow] = av.w;
    *(float4*)&Bs[brow][bcg] = bv;
    __syncthreads();
    #pragma unroll
    for (int k = 0; k < 16; ++k) {
      float4 a4 = *(const float4*)&AsT[k][ty * 4];
      float4 b4 = *(const float4*)&Bs[k][tx * 4];
      float a[4] = {a4.x, a4.y, a4.z, a4.w};
      float b[4] = {b4.x, b4.y, b4.z, b4.w};
      #pragma unroll
      for (int i = 0; i < 4; ++i)
        #pragma unroll
        for (int j = 0; j < 4; ++j)
          acc[i][j] += a[i] * b[j];
    }
  }
  #pragma unroll
  for (int i = 0; i < 4; ++i) {
    int r = row0 + ty * 4 + i;
    if (r < M) {
      float4 o = make_float4(acc[i][0], acc[i][1], acc[i][2], acc[i][3]);
      *(float4*)&C[(size_t)r * D + col0 + tx * 4] = o;
    }
  }
}

// ---------------- per-node attention logits: als/ald [N,H] ----------------

template<int H, int C>
__global__ __launch_bounds__(128) void attnlog_kernel(const float* __restrict__ h,
                                                      const float* __restrict__ a_src,
                                                      const float* __restrict__ a_dst,
                                                      float* __restrict__ als,
                                                      float* __restrict__ ald, int n_nodes) {
  constexpr int D = H * C;
  int n = blockIdx.x;
  int t = threadIdx.x;
  float hv = h[(size_t)n * D + t];
  float s = hv * a_src[t];
  float d = hv * a_dst[t];
  #pragma unroll
  for (int o = C / 2; o > 0; o >>= 1) {
    s += __shfl_xor(s, o, C);
    d += __shfl_xor(d, o, C);
  }
  if ((t & (C - 1)) == 0) {
    als[n * H + t / C] = s;
    ald[n * H + t / C] = d;
  }
}

// ---------------- per-dst-node softmax + weighted aggregation ----------------
// One 64-lane wave per destination node. Lane-parallel edge staging: lane j
// loads edge j's perm/src/ew/als and computes its logit in ONE parallel
// round-trip; weights live in registers; the accumulation loop broadcasts
// (src, w) via shuffle so the only memory op is the independent h-row gather
// (compiler keeps several in flight). deg > 64 handled by a rare tail path.

__device__ __forceinline__ float leaky02(float v) { return v > 0.f ? v : 0.2f * v; }

template<bool RELU>
__global__ __launch_bounds__(256) void aggregate4_kernel(const float* __restrict__ h,
                                                         const float* __restrict__ als,
                                                         const float* __restrict__ ald,
                                                         const float* __restrict__ ew,
                                                         const int* __restrict__ src,
                                                         const int* __restrict__ offsets,
                                                         const int* __restrict__ perm,
                                                         const float* __restrict__ bias,
                                                         float* __restrict__ out, int n_nodes) {
  int node = blockIdx.x * (blockDim.x >> 6) + (threadIdx.x >> 6);
  int lane = threadIdx.x & 63;
  if (node >= n_nodes) return;
  int start = offsets[node], end = offsets[node + 1];
  int deg = end - start;

  float4 aldv = *(const float4*)&ald[node * 4];

  // stage first chunk (covers deg <= 64: ~always for Poisson(16))
  int s0 = 0; float wgt0 = 0.f;
  float v0 = 0.f, v1 = 0.f, v2 = 0.f, v3 = 0.f;
  float m0 = -INFINITY, m1 = -INFINITY, m2 = -INFINITY, m3 = -INFINITY;
  if (lane < deg) {
    int e = perm[start + lane];
    s0 = src[e];
    wgt0 = ew[e];
    float4 a4 = *(const float4*)&als[s0 * 4];
    v0 = leaky02(a4.x + aldv.x); m0 = v0;
    v1 = leaky02(a4.y + aldv.y); m1 = v1;
    v2 = leaky02(a4.z + aldv.z); m2 = v2;
    v3 = leaky02(a4.w + aldv.w); m3 = v3;
  }
  // strided max for rare deg > 64
  for (int j = start + 64 + lane; j < end; j += 64) {
    int e = perm[j];
    int s = src[e];
    float4 a4 = *(const float4*)&als[s * 4];
    m0 = fmaxf(m0, leaky02(a4.x + aldv.x));
    m1 = fmaxf(m1, leaky02(a4.y + aldv.y));
    m2 = fmaxf(m2, leaky02(a4.z + aldv.z));
    m3 = fmaxf(m3, leaky02(a4.w + aldv.w));
  }
  #pragma unroll
  for (int o = 32; o > 0; o >>= 1) {
    m0 = fmaxf(m0, __shfl_xor(m0, o));
    m1 = fmaxf(m1, __shfl_xor(m1, o));
    m2 = fmaxf(m2, __shfl_xor(m2, o));
    m3 = fmaxf(m3, __shfl_xor(m3, o));
  }

  float w0 = 0.f, w1 = 0.f, w2 = 0.f, w3 = 0.f;
  if (lane < deg) {
    w0 = __expf(v0 - m0) * wgt0;
    w1 = __expf(v1 - m1) * wgt0;
    w2 = __expf(v2 - m2) * wgt0;
    w3 = __expf(v3 - m3) * wgt0;
  }

  int sel = lane >> 5;  // heads (sel, sel+2) for this lane's channel pair
  float accA = 0.f, accB = 0.f, dA = 0.f, dB = 0.f;
  int cn = deg < 64 ? deg : 64;
  #pragma unroll 4
  for (int j = 0; j < cn; ++j) {
    int sj = __shfl(s0, j);
    float t0 = __shfl(w0, j), t1 = __shfl(w1, j);
    float t2 = __shfl(w2, j), t3 = __shfl(w3, j);
    float wA = sel ? t1 : t0;
    float wB = sel ? t3 : t2;
    dA += wA; dB += wB;
    accA += wA * h[(size_t)sj * 128 + lane];
    accB += wB * h[(size_t)sj * 128 + 64 + lane];
  }
  // rare tail: deg > 64
  for (int base = start + 64; base < end; base += 64) {
    int cnt = end - base; if (cnt > 64) cnt = 64;
    int st = 0; float u0 = 0.f, u1 = 0.f, u2 = 0.f, u3 = 0.f;
    if (lane < cnt) {
      int e = perm[base + lane];
      st = src[e];
      float wg = ew[e];
      float4 a4 = *(const float4*)&als[st * 4];
      u0 = __expf(leaky02(a4.x + aldv.x) - m0) * wg;
      u1 = __expf(leaky02(a4.y + aldv.y) - m1) * wg;
      u2 = __expf(leaky02(a4.z + aldv.z) - m2) * wg;
      u3 = __expf(leaky02(a4.w + aldv.w) - m3) * wg;
    }
    #pragma unroll 4
    for (int j = 0; j < cnt; ++j) {
      int sj = __shfl(st, j);
      float t0 = __shfl(u0, j), t1 = __shfl(u1, j);
      float t2 = __shfl(u2, j), t3 = __shfl(u3, j);
      float wA = sel ? t1 : t0;
      float wB = sel ? t3 : t2;
      dA += wA; dB += wB;
      accA += wA * h[(size_t)sj * 128 + lane];
      accB += wB * h[(size_t)sj * 128 + 64 + lane];
    }
  }

  float oA = accA / (dA + 1e-16f) + bias[lane];
  float oB = accB / (dB + 1e-16f) + bias[64 + lane];
  if (RELU) { oA = fmaxf(oA, 0.f); oB = fmaxf(oB, 0.f); }
  out[(size_t)node * 128 + lane] = oA;
  out[(size_t)node * 128 + 64 + lane] = oB;
}

// H == 1, C == 64 variant (layer 3)
template<bool RELU>
__global__ __launch_bounds__(256) void aggregate1_kernel(const float* __restrict__ h,
                                                         const float* __restrict__ als,
                                                         const float* __restrict__ ald,
                                                         const float* __restrict__ ew,
                                                         const int* __restrict__ src,
                                                         const int* __restrict__ offsets,
                                                         const int* __restrict__ perm,
                                                         const float* __restrict__ bias,
                                                         float* __restrict__ out, int n_nodes) {
  int node = blockIdx.x * (blockDim.x >> 6) + (threadIdx.x >> 6);
  int lane = threadIdx.x & 63;
  if (node >= n_nodes) return;
  int start = offsets[node], end = offsets[node + 1];
  int deg = end - start;

  float ald0 = ald[node];
  int s0 = 0; float wgt0 = 0.f, v0 = 0.f, m0 = -INFINITY;
  if (lane < deg) {
    int e = perm[start + lane];
    s0 = src[e];
    wgt0 = ew[e];
    v0 = leaky02(als[s0] + ald0);
    m0 = v0;
  }
  for (int j = start + 64 + lane; j < end; j += 64) {
    int e = perm[j];
    int s = src[e];
    m0 = fmaxf(m0, leaky02(als[s] + ald0));
  }
  #pragma unroll
  for (int o = 32; o > 0; o >>= 1) m0 = fmaxf(m0, __shfl_xor(m0, o));

  float w0 = (lane < deg) ? __expf(v0 - m0) * wgt0 : 0.f;

  float acc = 0.f, dd = 0.f;
  int cn = deg < 64 ? deg : 64;
  #pragma unroll 4
  for (int j = 0; j < cn; ++j) {
    int sj = __shfl(s0, j);
    float wj = __shfl(w0, j);
    dd += wj;
    acc += wj * h[(size_t)sj * 64 + lane];
  }
  for (int base = start + 64; base < end; base += 64) {
    int cnt = end - base; if (cnt > 64) cnt = 64;
    int st = 0; float u0 = 0.f;
    if (lane < cnt) {
      int e = perm[base + lane];
      st = src[e];
      u0 = __expf(leaky02(als[st] + ald0) - m0) * ew[e];
    }
    #pragma unroll 4
    for (int j = 0; j < cnt; ++j) {
      int sj = __shfl(st, j);
      float wj = __shfl(u0, j);
      dd += wj;
      acc += wj * h[(size_t)sj * 64 + lane];
    }
  }

  float o = acc / (dd + 1e-16f) + bias[lane];
  if (RELU) o = fmaxf(o, 0.f);
  out[(size_t)node * 64 + lane] = o;
}

// ---------------- launch ----------------

extern "C" void kernel_launch(void* const* d_in, const int* in_sizes, int n_in,
                              void* d_out, int out_size, void* d_ws, size_t ws_size,
                              hipStream_t stream) {
  const int N = NNODES, E = NEDGES;
  const float* x   = (const float*)d_in[0];
  const int*   ei  = (const int*)d_in[1];
  const float* ew  = (const float*)d_in[2];
  const float* W1  = (const float*)d_in[3];
  const float* as1 = (const float*)d_in[4];
  const float* ad1 = (const float*)d_in[5];
  const float* b1  = (const float*)d_in[6];
  const float* W2  = (const float*)d_in[7];
  const float* as2 = (const float*)d_in[8];
  const float* ad2 = (const float*)d_in[9];
  const float* b2  = (const float*)d_in[10];
  const float* W3  = (const float*)d_in[11];
  const float* as3 = (const float*)d_in[12];
  const float* ad3 = (const float*)d_in[13];
  const float* b3  = (const float*)d_in[14];
  const int* src = ei;
  const int* dst = ei + E;

  uint8_t* p = (uint8_t*)d_ws;
  auto carve = [&](size_t bytes) {
    void* r = (void*)p;
    p += (bytes + 255) & ~(size_t)255;
    return r;
  };
  int*   counts  = (int*)carve((size_t)N * 4);
  int*   offsets = (int*)carve((size_t)(N + 1) * 4);
  int*   cursor  = (int*)carve((size_t)N * 4);
  int*   perm    = (int*)carve((size_t)E * 4);
  float* als     = (float*)carve((size_t)N * 4 * 4);
  float* ald     = (float*)carve((size_t)N * 4 * 4);
  float* hA      = (float*)carve((size_t)N * 128 * 4);
  float* hB      = (float*)carve((size_t)N * 128 * 4);

  // CSR by dst (edge list is identical every call but must be rebuilt in-launch)
  hipMemsetAsync(counts, 0, (size_t)N * 4, stream);
  hist_kernel<<<(E + 255) / 256, 256, 0, stream>>>(dst, counts, E);
  exscan_kernel<<<1, 256, 0, stream>>>(counts, offsets, cursor, N);
  scatter_kernel<<<(E + 255) / 256, 256, 0, stream>>>(dst, cursor, perm, E);

  int aggGrid = (N + 3) / 4;

  // layer 1: [N,256] @ [256,128], H=4 C=32, relu
  gemm_kernel<<<dim3((N + 63) / 64, 2), 256, 0, stream>>>(x, W1, hA, N, 256, 128);
  attnlog_kernel<4, 32><<<N, 128, 0, stream>>>(hA, as1, ad1, als, ald, N);
  aggregate4_kernel<true><<<aggGrid, 256, 0, stream>>>(hA, als, ald, ew, src, offsets,
                                                       perm, b1, hB, N);
  // layer 2: [N,128] @ [128,128], H=4 C=32, relu
  gemm_kernel<<<dim3((N + 63) / 64, 2), 256, 0, stream>>>(hB, W2, hA, N, 128, 128);
  attnlog_kernel<4, 32><<<N, 128, 0, stream>>>(hA, as2, ad2, als, ald, N);
  aggregate4_kernel<true><<<aggGrid, 256, 0, stream>>>(hA, als, ald, ew, src, offsets,
                                                       perm, b2, hB, N);
  // layer 3: [N,128] @ [128,64], H=1 C=64, no relu, output fp32
  gemm_kernel<<<dim3((N + 63) / 64, 1), 256, 0, stream>>>(hB, W3, hA, N, 128, 64);
  attnlog_kernel<1, 64><<<N, 64, 0, stream>>>(hA, as3, ad3, als, ald, N);
  aggregate1_kernel<false><<<aggGrid, 256, 0, stream>>>(hA, als, ald, ew, src, offsets,
                                                        perm, b3, (float*)d_out, N);
}

// Round 3
// 585.121 us; speedup vs baseline: 1.5107x; 1.1686x over previous
//
#include <hip/hip_runtime.h>
#include <hip/hip_bf16.h>
#include <math.h>

#define NNODES 50000
#define NEDGES 800000
#define SCAN_CHUNK 1024   // elements per block in the multi-block scan

// ---------------- CSR build (sort edges by dst) ----------------

__global__ __launch_bounds__(256) void hist_kernel(const int* __restrict__ dst,
                                                   int* __restrict__ counts, int ne) {
  int i = blockIdx.x * blockDim.x + threadIdx.x;
  if (i < ne) atomicAdd(&counts[dst[i]], 1);
}

// A: per-block reduction of SCAN_CHUNK counts -> blockSums[nb]
__global__ __launch_bounds__(256) void scan_reduce_kernel(const int* __restrict__ counts,
                                                          int* __restrict__ blockSums, int n) {
  int tid = threadIdx.x;
  int base = blockIdx.x * SCAN_CHUNK;
  int sum = 0;
  #pragma unroll
  for (int k = 0; k < SCAN_CHUNK / 256; ++k) {
    int i = base + k * 256 + tid;
    if (i < n) sum += counts[i];
  }
  #pragma unroll
  for (int o = 32; o > 0; o >>= 1) sum += __shfl_xor(sum, o);
  __shared__ int ws[4];
  if ((tid & 63) == 0) ws[tid >> 6] = sum;
  __syncthreads();
  if (tid == 0) blockSums[blockIdx.x] = ws[0] + ws[1] + ws[2] + ws[3];
}

// B: single tiny block — exclusive scan of blockSums (nb <= 64), writes offsets[n]
__global__ __launch_bounds__(64) void scan_spine_kernel(int* __restrict__ blockSums,
                                                        int* __restrict__ offsets,
                                                        int nb, int n) {
  int tid = threadIdx.x;
  int v = (tid < nb) ? blockSums[tid] : 0;
  int incl = v;
  #pragma unroll
  for (int o = 1; o < 64; o <<= 1) {
    int u = __shfl_up(incl, o, 64);
    if (tid >= o) incl += u;
  }
  if (tid < nb) blockSums[tid] = incl - v;      // exclusive prefix
  if (tid == 63) offsets[n] = incl;             // total
}

// C: per-block exclusive scan of its chunk + block prefix -> offsets, cursor
__global__ __launch_bounds__(256) void scan_write_kernel(const int* __restrict__ counts,
                                                         const int* __restrict__ blockSums,
                                                         int* __restrict__ offsets,
                                                         int* __restrict__ cursor, int n) {
  int tid = threadIdx.x;
  int base = blockIdx.x * SCAN_CHUNK;
  int i0 = base + tid * 4;
  int4 c = make_int4(0, 0, 0, 0);
  if (i0 + 3 < n) c = *(const int4*)&counts[i0];
  else {
    if (i0 + 0 < n) c.x = counts[i0 + 0];
    if (i0 + 1 < n) c.y = counts[i0 + 1];
    if (i0 + 2 < n) c.z = counts[i0 + 2];
    if (i0 + 3 < n) c.w = counts[i0 + 3];
  }
  int s = c.x + c.y + c.z + c.w;
  int lane = tid & 63, wid = tid >> 6;
  int incl = s;
  #pragma unroll
  for (int o = 1; o < 64; o <<= 1) {
    int u = __shfl_up(incl, o, 64);
    if (lane >= o) incl += u;
  }
  __shared__ int ws[4];
  if (lane == 63) ws[wid] = incl;
  __syncthreads();
  if (tid == 0) {
    int a = 0;
    #pragma unroll
    for (int w = 0; w < 4; ++w) { int t = ws[w]; ws[w] = a; a += t; }
  }
  __syncthreads();
  int run = blockSums[blockIdx.x] + ws[wid] + (incl - s);
  if (i0 + 0 < n) { offsets[i0 + 0] = run; cursor[i0 + 0] = run; run += c.x; }
  if (i0 + 1 < n) { offsets[i0 + 1] = run; cursor[i0 + 1] = run; run += c.y; }
  if (i0 + 2 < n) { offsets[i0 + 2] = run; cursor[i0 + 2] = run; run += c.z; }
  if (i0 + 3 < n) { offsets[i0 + 3] = run; cursor[i0 + 3] = run; run += c.w; }
}

__global__ __launch_bounds__(256) void scatter_kernel(const int* __restrict__ dst,
                                                      int* __restrict__ cursor,
                                                      int* __restrict__ perm, int ne) {
  int i = blockIdx.x * blockDim.x + threadIdx.x;
  if (i < ne) {
    int pos = atomicAdd(&cursor[dst[i]], 1);
    perm[pos] = i;
  }
}

// ---------------- fp32 tiled GEMM: C[M,D] = A[M,K] @ B[K,D] ----------------
// 64x64 tile, BK=16, 256 threads, 4x4 micro-tile. K % 16 == 0, D % 64 == 0.

__global__ __launch_bounds__(256) void gemm_kernel(const float* __restrict__ A,
                                                   const float* __restrict__ B,
                                                   float* __restrict__ C,
                                                   int M, int K, int D) {
  __shared__ float AsT[16][64];  // transposed A tile: [k][row]
  __shared__ float Bs[16][64];   // [k][col]
  int tid = threadIdx.x;
  int tx = tid & 15, ty = tid >> 4;
  int row0 = blockIdx.x * 64, col0 = blockIdx.y * 64;
  float acc[4][4] = {};

  int arow = tid >> 2;        // 0..63
  int acg  = (tid & 3) * 4;   // 0,4,8,12
  int brow = tid >> 4;        // 0..15
  int bcg  = (tid & 15) * 4;  // 0..60
  int grow = row0 + arow;

  for (int k0 = 0; k0 < K; k0 += 16) {
    float4 av;
    if (grow < M) av = *(const float4*)&A[(size_t)grow * K + k0 + acg];
    else          av = make_float4(0.f, 0.f, 0.f, 0.f);
    float4 bv = *(const float4*)&B[(size_t)(k0 + brow) * D + col0 + bcg];
    __syncthreads();
    AsT[acg + 0][arow] = av.x;
    AsT[acg + 1][arow] = av.y;
    AsT[acg + 2][arow] = av.z;
    AsT[acg + 3][arow] = av.w;
    *(float4*)&Bs[brow][bcg] = bv;
    __syncthreads();
    #pragma unroll
    for (int k = 0; k < 16; ++k) {
      float4 a4 = *(const float4*)&AsT[k][ty * 4];
      float4 b4 = *(const float4*)&Bs[k][tx * 4];
      float a[4] = {a4.x, a4.y, a4.z, a4.w};
      float b[4] = {b4.x, b4.y, b4.z, b4.w};
      #pragma unroll
      for (int i = 0; i < 4; ++i)
        #pragma unroll
        for (int j = 0; j < 4; ++j)
          acc[i][j] += a[i] * b[j];
    }
  }
  #pragma unroll
  for (int i = 0; i < 4; ++i) {
    int r = row0 + ty * 4 + i;
    if (r < M) {
      float4 o = make_float4(acc[i][0], acc[i][1], acc[i][2], acc[i][3]);
      *(float4*)&C[(size_t)r * D + col0 + tx * 4] = o;
    }
  }
}

// ---------------- per-node attention logits: als/ald [N,H] ----------------

template<int H, int C>
__global__ __launch_bounds__(128) void attnlog_kernel(const float* __restrict__ h,
                                                      const float* __restrict__ a_src,
                                                      const float* __restrict__ a_dst,
                                                      float* __restrict__ als,
                                                      float* __restrict__ ald, int n_nodes) {
  constexpr int D = H * C;
  int n = blockIdx.x;
  int t = threadIdx.x;
  float hv = h[(size_t)n * D + t];
  float s = hv * a_src[t];
  float d = hv * a_dst[t];
  #pragma unroll
  for (int o = C / 2; o > 0; o >>= 1) {
    s += __shfl_xor(s, o, C);
    d += __shfl_xor(d, o, C);
  }
  if ((t & (C - 1)) == 0) {
    als[n * H + t / C] = s;
    ald[n * H + t / C] = d;
  }
}

// ---------------- per-dst-node softmax + weighted aggregation ----------------

__device__ __forceinline__ float leaky02(float v) { return v > 0.f ? v : 0.2f * v; }

template<bool RELU>
__global__ __launch_bounds__(256) void aggregate4_kernel(const float* __restrict__ h,
                                                         const float* __restrict__ als,
                                                         const float* __restrict__ ald,
                                                         const float* __restrict__ ew,
                                                         const int* __restrict__ src,
                                                         const int* __restrict__ offsets,
                                                         const int* __restrict__ perm,
                                                         const float* __restrict__ bias,
                                                         float* __restrict__ out, int n_nodes) {
  int node = blockIdx.x * (blockDim.x >> 6) + (threadIdx.x >> 6);
  int lane = threadIdx.x & 63;
  if (node >= n_nodes) return;
  int start = offsets[node], end = offsets[node + 1];
  int deg = end - start;

  float4 aldv = *(const float4*)&ald[node * 4];

  // stage first chunk (covers deg <= 64: ~always for Poisson(16))
  int s0 = 0; float wgt0 = 0.f;
  float v0 = 0.f, v1 = 0.f, v2 = 0.f, v3 = 0.f;
  float m0 = -INFINITY, m1 = -INFINITY, m2 = -INFINITY, m3 = -INFINITY;
  if (lane < deg) {
    int e = perm[start + lane];
    s0 = src[e];
    wgt0 = ew[e];
    float4 a4 = *(const float4*)&als[s0 * 4];
    v0 = leaky02(a4.x + aldv.x); m0 = v0;
    v1 = leaky02(a4.y + aldv.y); m1 = v1;
    v2 = leaky02(a4.z + aldv.z); m2 = v2;
    v3 = leaky02(a4.w + aldv.w); m3 = v3;
  }
  // strided max for rare deg > 64
  for (int j = start + 64 + lane; j < end; j += 64) {
    int e = perm[j];
    int s = src[e];
    float4 a4 = *(const float4*)&als[s * 4];
    m0 = fmaxf(m0, leaky02(a4.x + aldv.x));
    m1 = fmaxf(m1, leaky02(a4.y + aldv.y));
    m2 = fmaxf(m2, leaky02(a4.z + aldv.z));
    m3 = fmaxf(m3, leaky02(a4.w + aldv.w));
  }
  #pragma unroll
  for (int o = 32; o > 0; o >>= 1) {
    m0 = fmaxf(m0, __shfl_xor(m0, o));
    m1 = fmaxf(m1, __shfl_xor(m1, o));
    m2 = fmaxf(m2, __shfl_xor(m2, o));
    m3 = fmaxf(m3, __shfl_xor(m3, o));
  }

  float w0 = 0.f, w1 = 0.f, w2 = 0.f, w3 = 0.f;
  if (lane < deg) {
    w0 = __expf(v0 - m0) * wgt0;
    w1 = __expf(v1 - m1) * wgt0;
    w2 = __expf(v2 - m2) * wgt0;
    w3 = __expf(v3 - m3) * wgt0;
  }

  int sel = lane >> 5;  // heads (sel, sel+2) for this lane's channel pair
  float accA = 0.f, accB = 0.f, dA = 0.f, dB = 0.f;
  int cn = deg < 64 ? deg : 64;
  #pragma unroll 4
  for (int j = 0; j < cn; ++j) {
    int sj = __shfl(s0, j);
    float t0 = __shfl(w0, j), t1 = __shfl(w1, j);
    float t2 = __shfl(w2, j), t3 = __shfl(w3, j);
    float wA = sel ? t1 : t0;
    float wB = sel ? t3 : t2;
    dA += wA; dB += wB;
    accA += wA * h[(size_t)sj * 128 + lane];
    accB += wB * h[(size_t)sj * 128 + 64 + lane];
  }
  // rare tail: deg > 64
  for (int base = start + 64; base < end; base += 64) {
    int cnt = end - base; if (cnt > 64) cnt = 64;
    int st = 0; float u0 = 0.f, u1 = 0.f, u2 = 0.f, u3 = 0.f;
    if (lane < cnt) {
      int e = perm[base + lane];
      st = src[e];
      float wg = ew[e];
      float4 a4 = *(const float4*)&als[st * 4];
      u0 = __expf(leaky02(a4.x + aldv.x) - m0) * wg;
      u1 = __expf(leaky02(a4.y + aldv.y) - m1) * wg;
      u2 = __expf(leaky02(a4.z + aldv.z) - m2) * wg;
      u3 = __expf(leaky02(a4.w + aldv.w) - m3) * wg;
    }
    #pragma unroll 4
    for (int j = 0; j < cnt; ++j) {
      int sj = __shfl(st, j);
      float t0 = __shfl(u0, j), t1 = __shfl(u1, j);
      float t2 = __shfl(u2, j), t3 = __shfl(u3, j);
      float wA = sel ? t1 : t0;
      float wB = sel ? t3 : t2;
      dA += wA; dB += wB;
      accA += wA * h[(size_t)sj * 128 + lane];
      accB += wB * h[(size_t)sj * 128 + 64 + lane];
    }
  }

  float oA = accA / (dA + 1e-16f) + bias[lane];
  float oB = accB / (dB + 1e-16f) + bias[64 + lane];
  if (RELU) { oA = fmaxf(oA, 0.f); oB = fmaxf(oB, 0.f); }
  out[(size_t)node * 128 + lane] = oA;
  out[(size_t)node * 128 + 64 + lane] = oB;
}

// H == 1, C == 64 variant (layer 3)
template<bool RELU>
__global__ __launch_bounds__(256) void aggregate1_kernel(const float* __restrict__ h,
                                                         const float* __restrict__ als,
                                                         const float* __restrict__ ald,
                                                         const float* __restrict__ ew,
                                                         const int* __restrict__ src,
                                                         const int* __restrict__ offsets,
                                                         const int* __restrict__ perm,
                                                         const float* __restrict__ bias,
                                                         float* __restrict__ out, int n_nodes) {
  int node = blockIdx.x * (blockDim.x >> 6) + (threadIdx.x >> 6);
  int lane = threadIdx.x & 63;
  if (node >= n_nodes) return;
  int start = offsets[node], end = offsets[node + 1];
  int deg = end - start;

  float ald0 = ald[node];
  int s0 = 0; float wgt0 = 0.f, v0 = 0.f, m0 = -INFINITY;
  if (lane < deg) {
    int e = perm[start + lane];
    s0 = src[e];
    wgt0 = ew[e];
    v0 = leaky02(als[s0] + ald0);
    m0 = v0;
  }
  for (int j = start + 64 + lane; j < end; j += 64) {
    int e = perm[j];
    int s = src[e];
    m0 = fmaxf(m0, leaky02(als[s] + ald0));
  }
  #pragma unroll
  for (int o = 32; o > 0; o >>= 1) m0 = fmaxf(m0, __shfl_xor(m0, o));

  float w0 = (lane < deg) ? __expf(v0 - m0) * wgt0 : 0.f;

  float acc = 0.f, dd = 0.f;
  int cn = deg < 64 ? deg : 64;
  #pragma unroll 4
  for (int j = 0; j < cn; ++j) {
    int sj = __shfl(s0, j);
    float wj = __shfl(w0, j);
    dd += wj;
    acc += wj * h[(size_t)sj * 64 + lane];
  }
  for (int base = start + 64; base < end; base += 64) {
    int cnt = end - base; if (cnt > 64) cnt = 64;
    int st = 0; float u0 = 0.f;
    if (lane < cnt) {
      int e = perm[base + lane];
      st = src[e];
      u0 = __expf(leaky02(als[st] + ald0) - m0) * ew[e];
    }
    #pragma unroll 4
    for (int j = 0; j < cnt; ++j) {
      int sj = __shfl(st, j);
      float wj = __shfl(u0, j);
      dd += wj;
      acc += wj * h[(size_t)sj * 64 + lane];
    }
  }

  float o = acc / (dd + 1e-16f) + bias[lane];
  if (RELU) o = fmaxf(o, 0.f);
  out[(size_t)node * 64 + lane] = o;
}

// ---------------- launch ----------------

extern "C" void kernel_launch(void* const* d_in, const int* in_sizes, int n_in,
                              void* d_out, int out_size, void* d_ws, size_t ws_size,
                              hipStream_t stream) {
  const int N = NNODES, E = NEDGES;
  const float* x   = (const float*)d_in[0];
  const int*   ei  = (const int*)d_in[1];
  const float* ew  = (const float*)d_in[2];
  const float* W1  = (const float*)d_in[3];
  const float* as1 = (const float*)d_in[4];
  const float* ad1 = (const float*)d_in[5];
  const float* b1  = (const float*)d_in[6];
  const float* W2  = (const float*)d_in[7];
  const float* as2 = (const float*)d_in[8];
  const float* ad2 = (const float*)d_in[9];
  const float* b2  = (const float*)d_in[10];
  const float* W3  = (const float*)d_in[11];
  const float* as3 = (const float*)d_in[12];
  const float* ad3 = (const float*)d_in[13];
  const float* b3  = (const float*)d_in[14];
  const int* src = ei;
  const int* dst = ei + E;

  uint8_t* p = (uint8_t*)d_ws;
  auto carve = [&](size_t bytes) {
    void* r = (void*)p;
    p += (bytes + 255) & ~(size_t)255;
    return r;
  };
  int*   counts  = (int*)carve((size_t)N * 4);
  int*   offsets = (int*)carve((size_t)(N + 1) * 4);
  int*   cursor  = (int*)carve((size_t)N * 4);
  int*   perm    = (int*)carve((size_t)E * 4);
  int*   bsums   = (int*)carve((size_t)256 * 4);
  float* als     = (float*)carve((size_t)N * 4 * 4);
  float* ald     = (float*)carve((size_t)N * 4 * 4);
  float* hA      = (float*)carve((size_t)N * 128 * 4);
  float* hB      = (float*)carve((size_t)N * 128 * 4);

  // CSR by dst (edge list is identical every call but must be rebuilt in-launch)
  int nb = (N + SCAN_CHUNK - 1) / SCAN_CHUNK;   // 49 <= 64
  hipMemsetAsync(counts, 0, (size_t)N * 4, stream);
  hist_kernel<<<(E + 255) / 256, 256, 0, stream>>>(dst, counts, E);
  scan_reduce_kernel<<<nb, 256, 0, stream>>>(counts, bsums, N);
  scan_spine_kernel<<<1, 64, 0, stream>>>(bsums, offsets, nb, N);
  scan_write_kernel<<<nb, 256, 0, stream>>>(counts, bsums, offsets, cursor, N);
  scatter_kernel<<<(E + 255) / 256, 256, 0, stream>>>(dst, cursor, perm, E);

  int aggGrid = (N + 3) / 4;

  // layer 1: [N,256] @ [256,128], H=4 C=32, relu
  gemm_kernel<<<dim3((N + 63) / 64, 2), 256, 0, stream>>>(x, W1, hA, N, 256, 128);
  attnlog_kernel<4, 32><<<N, 128, 0, stream>>>(hA, as1, ad1, als, ald, N);
  aggregate4_kernel<true><<<aggGrid, 256, 0, stream>>>(hA, als, ald, ew, src, offsets,
                                                       perm, b1, hB, N);
  // layer 2: [N,128] @ [128,128], H=4 C=32, relu
  gemm_kernel<<<dim3((N + 63) / 64, 2), 256, 0, stream>>>(hB, W2, hA, N, 128, 128);
  attnlog_kernel<4, 32><<<N, 128, 0, stream>>>(hA, as2, ad2, als, ald, N);
  aggregate4_kernel<true><<<aggGrid, 256, 0, stream>>>(hA, als, ald, ew, src, offsets,
                                                       perm, b2, hB, N);
  // layer 3: [N,128] @ [128,64], H=1 C=64, no relu, output fp32
  gemm_kernel<<<dim3((N + 63) / 64, 1), 256, 0, stream>>>(hB, W3, hA, N, 128, 64);
  attnlog_kernel<1, 64><<<N, 64, 0, stream>>>(hA, as3, ad3, als, ald, N);
  aggregate1_kernel<false><<<aggGrid, 256, 0, stream>>>(hA, als, ald, ew, src, offsets,
                                                        perm, b3, (float*)d_out, N);
}

// Round 4
// 562.500 us; speedup vs baseline: 1.5714x; 1.0402x over previous
//
#include <hip/hip_runtime.h>
#include <hip/hip_bf16.h>
#include <math.h>

#define NNODES 50000
#define NEDGES 800000
#define SCAN_CHUNK 1024   // elements per block in the multi-block scan

// ---------------- CSR build (sort edges by dst) ----------------

__global__ __launch_bounds__(256) void hist_kernel(const int* __restrict__ dst,
                                                   int* __restrict__ counts, int ne) {
  int i = blockIdx.x * blockDim.x + threadIdx.x;
  if (i < ne) atomicAdd(&counts[dst[i]], 1);
}

// A: per-block reduction of SCAN_CHUNK counts -> blockSums[nb]
__global__ __launch_bounds__(256) void scan_reduce_kernel(const int* __restrict__ counts,
                                                          int* __restrict__ blockSums, int n) {
  int tid = threadIdx.x;
  int base = blockIdx.x * SCAN_CHUNK;
  int sum = 0;
  #pragma unroll
  for (int k = 0; k < SCAN_CHUNK / 256; ++k) {
    int i = base + k * 256 + tid;
    if (i < n) sum += counts[i];
  }
  #pragma unroll
  for (int o = 32; o > 0; o >>= 1) sum += __shfl_xor(sum, o);
  __shared__ int ws[4];
  if ((tid & 63) == 0) ws[tid >> 6] = sum;
  __syncthreads();
  if (tid == 0) blockSums[blockIdx.x] = ws[0] + ws[1] + ws[2] + ws[3];
}

// B: single tiny block — exclusive scan of blockSums (nb <= 64), writes offsets[n]
__global__ __launch_bounds__(64) void scan_spine_kernel(int* __restrict__ blockSums,
                                                        int* __restrict__ offsets,
                                                        int nb, int n) {
  int tid = threadIdx.x;
  int v = (tid < nb) ? blockSums[tid] : 0;
  int incl = v;
  #pragma unroll
  for (int o = 1; o < 64; o <<= 1) {
    int u = __shfl_up(incl, o, 64);
    if (tid >= o) incl += u;
  }
  if (tid < nb) blockSums[tid] = incl - v;      // exclusive prefix
  if (tid == 63) offsets[n] = incl;             // total
}

// C: per-block exclusive scan of its chunk + block prefix -> offsets, cursor
__global__ __launch_bounds__(256) void scan_write_kernel(const int* __restrict__ counts,
                                                         const int* __restrict__ blockSums,
                                                         int* __restrict__ offsets,
                                                         int* __restrict__ cursor, int n) {
  int tid = threadIdx.x;
  int base = blockIdx.x * SCAN_CHUNK;
  int i0 = base + tid * 4;
  int4 c = make_int4(0, 0, 0, 0);
  if (i0 + 3 < n) c = *(const int4*)&counts[i0];
  else {
    if (i0 + 0 < n) c.x = counts[i0 + 0];
    if (i0 + 1 < n) c.y = counts[i0 + 1];
    if (i0 + 2 < n) c.z = counts[i0 + 2];
    if (i0 + 3 < n) c.w = counts[i0 + 3];
  }
  int s = c.x + c.y + c.z + c.w;
  int lane = tid & 63, wid = tid >> 6;
  int incl = s;
  #pragma unroll
  for (int o = 1; o < 64; o <<= 1) {
    int u = __shfl_up(incl, o, 64);
    if (lane >= o) incl += u;
  }
  __shared__ int ws[4];
  if (lane == 63) ws[wid] = incl;
  __syncthreads();
  if (tid == 0) {
    int a = 0;
    #pragma unroll
    for (int w = 0; w < 4; ++w) { int t = ws[w]; ws[w] = a; a += t; }
  }
  __syncthreads();
  int run = blockSums[blockIdx.x] + ws[wid] + (incl - s);
  if (i0 + 0 < n) { offsets[i0 + 0] = run; cursor[i0 + 0] = run; run += c.x; }
  if (i0 + 1 < n) { offsets[i0 + 1] = run; cursor[i0 + 1] = run; run += c.y; }
  if (i0 + 2 < n) { offsets[i0 + 2] = run; cursor[i0 + 2] = run; run += c.z; }
  if (i0 + 3 < n) { offsets[i0 + 3] = run; cursor[i0 + 3] = run; run += c.w; }
}

__global__ __launch_bounds__(256) void scatter_kernel(const int* __restrict__ dst,
                                                      int* __restrict__ cursor,
                                                      int* __restrict__ perm, int ne) {
  int i = blockIdx.x * blockDim.x + threadIdx.x;
  if (i < ne) {
    int pos = atomicAdd(&cursor[dst[i]], 1);
    perm[pos] = i;
  }
}

// ---------------- fp32 GEMM 128x128 tile (D % 128 == 0, K % 16 == 0) -------
// 256 threads, 2x2 blocks of 4x4 micro-tiles (split +-64 => LDS reads are
// 2-way-conflict-free, global loads 256B-coalesced). Compute-bound design.

__global__ __launch_bounds__(256) void gemm128_kernel(const float* __restrict__ A,
                                                      const float* __restrict__ B,
                                                      float* __restrict__ C,
                                                      int M, int K, int D) {
  __shared__ float AsT[16][128];  // [k][row]
  __shared__ float Bs[16][128];   // [k][col]
  int tid = threadIdx.x;
  int tx = tid & 15, ty = tid >> 4;
  int row0 = blockIdx.x * 128, col0 = blockIdx.y * 128;
  float acc[2][2][4][4] = {};

  int arow = tid >> 1;            // 0..127
  int acg  = (tid & 1) * 8;       // 0 or 8
  int brow = tid >> 4;            // 0..15
  int bcg  = (tid & 15) * 4;      // 0..60
  int grow = row0 + arow;

  for (int k0 = 0; k0 < K; k0 += 16) {
    float4 av0, av1, bv0, bv1;
    if (grow < M) {
      av0 = *(const float4*)&A[(size_t)grow * K + k0 + acg];
      av1 = *(const float4*)&A[(size_t)grow * K + k0 + acg + 4];
    } else {
      av0 = make_float4(0.f, 0.f, 0.f, 0.f);
      av1 = av0;
    }
    bv0 = *(const float4*)&B[(size_t)(k0 + brow) * D + col0 + bcg];
    bv1 = *(const float4*)&B[(size_t)(k0 + brow) * D + col0 + 64 + bcg];
    __syncthreads();
    AsT[acg + 0][arow] = av0.x;
    AsT[acg + 1][arow] = av0.y;
    AsT[acg + 2][arow] = av0.z;
    AsT[acg + 3][arow] = av0.w;
    AsT[acg + 4][arow] = av1.x;
    AsT[acg + 5][arow] = av1.y;
    AsT[acg + 6][arow] = av1.z;
    AsT[acg + 7][arow] = av1.w;
    *(float4*)&Bs[brow][bcg] = bv0;
    *(float4*)&Bs[brow][64 + bcg] = bv1;
    __syncthreads();
    #pragma unroll
    for (int k = 0; k < 16; ++k) {
      float4 a0 = *(const float4*)&AsT[k][ty * 4];
      float4 a1 = *(const float4*)&AsT[k][64 + ty * 4];
      float4 b0 = *(const float4*)&Bs[k][tx * 4];
      float4 b1 = *(const float4*)&Bs[k][64 + tx * 4];
      float ar[2][4] = {{a0.x, a0.y, a0.z, a0.w}, {a1.x, a1.y, a1.z, a1.w}};
      float br[2][4] = {{b0.x, b0.y, b0.z, b0.w}, {b1.x, b1.y, b1.z, b1.w}};
      #pragma unroll
      for (int rh = 0; rh < 2; ++rh)
        #pragma unroll
        for (int ch = 0; ch < 2; ++ch)
          #pragma unroll
          for (int i = 0; i < 4; ++i)
            #pragma unroll
            for (int j = 0; j < 4; ++j)
              acc[rh][ch][i][j] += ar[rh][i] * br[ch][j];
    }
  }
  #pragma unroll
  for (int rh = 0; rh < 2; ++rh)
    #pragma unroll
    for (int i = 0; i < 4; ++i) {
      int r = row0 + rh * 64 + ty * 4 + i;
      if (r < M) {
        *(float4*)&C[(size_t)r * D + col0 + tx * 4] =
            make_float4(acc[rh][0][i][0], acc[rh][0][i][1], acc[rh][0][i][2], acc[rh][0][i][3]);
        *(float4*)&C[(size_t)r * D + col0 + 64 + tx * 4] =
            make_float4(acc[rh][1][i][0], acc[rh][1][i][1], acc[rh][1][i][2], acc[rh][1][i][3]);
      }
    }
}

// ---------------- fp32 tiled GEMM 64x64 (layer 3, D=64) ----------------

__global__ __launch_bounds__(256) void gemm_kernel(const float* __restrict__ A,
                                                   const float* __restrict__ B,
                                                   float* __restrict__ C,
                                                   int M, int K, int D) {
  __shared__ float AsT[16][64];
  __shared__ float Bs[16][64];
  int tid = threadIdx.x;
  int tx = tid & 15, ty = tid >> 4;
  int row0 = blockIdx.x * 64, col0 = blockIdx.y * 64;
  float acc[4][4] = {};

  int arow = tid >> 2;
  int acg  = (tid & 3) * 4;
  int brow = tid >> 4;
  int bcg  = (tid & 15) * 4;
  int grow = row0 + arow;

  for (int k0 = 0; k0 < K; k0 += 16) {
    float4 av;
    if (grow < M) av = *(const float4*)&A[(size_t)grow * K + k0 + acg];
    else          av = make_float4(0.f, 0.f, 0.f, 0.f);
    float4 bv = *(const float4*)&B[(size_t)(k0 + brow) * D + col0 + bcg];
    __syncthreads();
    AsT[acg + 0][arow] = av.x;
    AsT[acg + 1][arow] = av.y;
    AsT[acg + 2][arow] = av.z;
    AsT[acg + 3][arow] = av.w;
    *(float4*)&Bs[brow][bcg] = bv;
    __syncthreads();
    #pragma unroll
    for (int k = 0; k < 16; ++k) {
      float4 a4 = *(const float4*)&AsT[k][ty * 4];
      float4 b4 = *(const float4*)&Bs[k][tx * 4];
      float a[4] = {a4.x, a4.y, a4.z, a4.w};
      float b[4] = {b4.x, b4.y, b4.z, b4.w};
      #pragma unroll
      for (int i = 0; i < 4; ++i)
        #pragma unroll
        for (int j = 0; j < 4; ++j)
          acc[i][j] += a[i] * b[j];
    }
  }
  #pragma unroll
  for (int i = 0; i < 4; ++i) {
    int r = row0 + ty * 4 + i;
    if (r < M) {
      float4 o = make_float4(acc[i][0], acc[i][1], acc[i][2], acc[i][3]);
      *(float4*)&C[(size_t)r * D + col0 + tx * 4] = o;
    }
  }
}

// ---------------- per-node attention logits: als/ald [N,H] ----------------

template<int H, int C>
__global__ __launch_bounds__(128) void attnlog_kernel(const float* __restrict__ h,
                                                      const float* __restrict__ a_src,
                                                      const float* __restrict__ a_dst,
                                                      float* __restrict__ als,
                                                      float* __restrict__ ald, int n_nodes) {
  constexpr int D = H * C;
  int n = blockIdx.x;
  int t = threadIdx.x;
  float hv = h[(size_t)n * D + t];
  float s = hv * a_src[t];
  float d = hv * a_dst[t];
  #pragma unroll
  for (int o = C / 2; o > 0; o >>= 1) {
    s += __shfl_xor(s, o, C);
    d += __shfl_xor(d, o, C);
  }
  if ((t & (C - 1)) == 0) {
    als[n * H + t / C] = s;
    ald[n * H + t / C] = d;
  }
}

// ---------------- per-dst-node softmax + weighted aggregation ----------------
// One 64-lane wave per node; lane-parallel edge staging; unroll-by-8 gather
// batching so ~16 global loads are in flight per wave before the FMAs.

__device__ __forceinline__ float leaky02(float v) { return v > 0.f ? v : 0.2f * v; }

template<bool RELU>
__global__ __launch_bounds__(256) void aggregate4_kernel(const float* __restrict__ h,
                                                         const float* __restrict__ als,
                                                         const float* __restrict__ ald,
                                                         const float* __restrict__ ew,
                                                         const int* __restrict__ src,
                                                         const int* __restrict__ offsets,
                                                         const int* __restrict__ perm,
                                                         const float* __restrict__ bias,
                                                         float* __restrict__ out, int n_nodes) {
  int node = blockIdx.x * (blockDim.x >> 6) + (threadIdx.x >> 6);
  int lane = threadIdx.x & 63;
  if (node >= n_nodes) return;
  int start = offsets[node], end = offsets[node + 1];
  int deg = end - start;

  float4 aldv = *(const float4*)&ald[node * 4];

  // stage first chunk (covers deg <= 64: ~always for Poisson(16))
  int s0 = 0; float wgt0 = 0.f;
  float v0 = 0.f, v1 = 0.f, v2 = 0.f, v3 = 0.f;
  float m0 = -INFINITY, m1 = -INFINITY, m2 = -INFINITY, m3 = -INFINITY;
  if (lane < deg) {
    int e = perm[start + lane];
    s0 = src[e];
    wgt0 = ew[e];
    float4 a4 = *(const float4*)&als[s0 * 4];
    v0 = leaky02(a4.x + aldv.x); m0 = v0;
    v1 = leaky02(a4.y + aldv.y); m1 = v1;
    v2 = leaky02(a4.z + aldv.z); m2 = v2;
    v3 = leaky02(a4.w + aldv.w); m3 = v3;
  }
  // strided max for rare deg > 64
  for (int j = start + 64 + lane; j < end; j += 64) {
    int e = perm[j];
    int s = src[e];
    float4 a4 = *(const float4*)&als[s * 4];
    m0 = fmaxf(m0, leaky02(a4.x + aldv.x));
    m1 = fmaxf(m1, leaky02(a4.y + aldv.y));
    m2 = fmaxf(m2, leaky02(a4.z + aldv.z));
    m3 = fmaxf(m3, leaky02(a4.w + aldv.w));
  }
  #pragma unroll
  for (int o = 32; o > 0; o >>= 1) {
    m0 = fmaxf(m0, __shfl_xor(m0, o));
    m1 = fmaxf(m1, __shfl_xor(m1, o));
    m2 = fmaxf(m2, __shfl_xor(m2, o));
    m3 = fmaxf(m3, __shfl_xor(m3, o));
  }

  float w0 = 0.f, w1 = 0.f, w2 = 0.f, w3 = 0.f;
  if (lane < deg) {
    w0 = __expf(v0 - m0) * wgt0;
    w1 = __expf(v1 - m1) * wgt0;
    w2 = __expf(v2 - m2) * wgt0;
    w3 = __expf(v3 - m3) * wgt0;
  }

  int sel = lane >> 5;  // heads (sel, sel+2) for this lane's channel pair
  float accA = 0.f, accB = 0.f, dA = 0.f, dB = 0.f;
  int cn = deg < 64 ? deg : 64;
  int j = 0;
  for (; j + 8 <= cn; j += 8) {
    float hA_[8], hB_[8], wA_[8], wB_[8];
    #pragma unroll
    for (int u = 0; u < 8; ++u) {
      int sj = __shfl(s0, j + u);
      float t0 = __shfl(w0, j + u), t1 = __shfl(w1, j + u);
      float t2 = __shfl(w2, j + u), t3 = __shfl(w3, j + u);
      wA_[u] = sel ? t1 : t0;
      wB_[u] = sel ? t3 : t2;
      const float* hp = &h[(size_t)sj * 128 + lane];
      hA_[u] = hp[0];
      hB_[u] = hp[64];
    }
    #pragma unroll
    for (int u = 0; u < 8; ++u) {
      dA += wA_[u]; dB += wB_[u];
      accA += wA_[u] * hA_[u];
      accB += wB_[u] * hB_[u];
    }
  }
  for (; j < cn; ++j) {
    int sj = __shfl(s0, j);
    float t0 = __shfl(w0, j), t1 = __shfl(w1, j);
    float t2 = __shfl(w2, j), t3 = __shfl(w3, j);
    float wA = sel ? t1 : t0;
    float wB = sel ? t3 : t2;
    dA += wA; dB += wB;
    accA += wA * h[(size_t)sj * 128 + lane];
    accB += wB * h[(size_t)sj * 128 + 64 + lane];
  }
  // rare tail: deg > 64
  for (int base = start + 64; base < end; base += 64) {
    int cnt = end - base; if (cnt > 64) cnt = 64;
    int st = 0; float u0 = 0.f, u1 = 0.f, u2 = 0.f, u3 = 0.f;
    if (lane < cnt) {
      int e = perm[base + lane];
      st = src[e];
      float wg = ew[e];
      float4 a4 = *(const float4*)&als[st * 4];
      u0 = __expf(leaky02(a4.x + aldv.x) - m0) * wg;
      u1 = __expf(leaky02(a4.y + aldv.y) - m1) * wg;
      u2 = __expf(leaky02(a4.z + aldv.z) - m2) * wg;
      u3 = __expf(leaky02(a4.w + aldv.w) - m3) * wg;
    }
    #pragma unroll 4
    for (int jj = 0; jj < cnt; ++jj) {
      int sj = __shfl(st, jj);
      float t0 = __shfl(u0, jj), t1 = __shfl(u1, jj);
      float t2 = __shfl(u2, jj), t3 = __shfl(u3, jj);
      float wA = sel ? t1 : t0;
      float wB = sel ? t3 : t2;
      dA += wA; dB += wB;
      accA += wA * h[(size_t)sj * 128 + lane];
      accB += wB * h[(size_t)sj * 128 + 64 + lane];
    }
  }

  float oA = accA / (dA + 1e-16f) + bias[lane];
  float oB = accB / (dB + 1e-16f) + bias[64 + lane];
  if (RELU) { oA = fmaxf(oA, 0.f); oB = fmaxf(oB, 0.f); }
  out[(size_t)node * 128 + lane] = oA;
  out[(size_t)node * 128 + 64 + lane] = oB;
}

// H == 1, C == 64 variant (layer 3)
template<bool RELU>
__global__ __launch_bounds__(256) void aggregate1_kernel(const float* __restrict__ h,
                                                         const float* __restrict__ als,
                                                         const float* __restrict__ ald,
                                                         const float* __restrict__ ew,
                                                         const int* __restrict__ src,
                                                         const int* __restrict__ offsets,
                                                         const int* __restrict__ perm,
                                                         const float* __restrict__ bias,
                                                         float* __restrict__ out, int n_nodes) {
  int node = blockIdx.x * (blockDim.x >> 6) + (threadIdx.x >> 6);
  int lane = threadIdx.x & 63;
  if (node >= n_nodes) return;
  int start = offsets[node], end = offsets[node + 1];
  int deg = end - start;

  float ald0 = ald[node];
  int s0 = 0; float wgt0 = 0.f, v0 = 0.f, m0 = -INFINITY;
  if (lane < deg) {
    int e = perm[start + lane];
    s0 = src[e];
    wgt0 = ew[e];
    v0 = leaky02(als[s0] + ald0);
    m0 = v0;
  }
  for (int j = start + 64 + lane; j < end; j += 64) {
    int e = perm[j];
    int s = src[e];
    m0 = fmaxf(m0, leaky02(als[s] + ald0));
  }
  #pragma unroll
  for (int o = 32; o > 0; o >>= 1) m0 = fmaxf(m0, __shfl_xor(m0, o));

  float w0 = (lane < deg) ? __expf(v0 - m0) * wgt0 : 0.f;

  float acc = 0.f, dd = 0.f;
  int cn = deg < 64 ? deg : 64;
  int j = 0;
  for (; j + 8 <= cn; j += 8) {
    float hv[8], wv[8];
    #pragma unroll
    for (int u = 0; u < 8; ++u) {
      int sj = __shfl(s0, j + u);
      wv[u] = __shfl(w0, j + u);
      hv[u] = h[(size_t)sj * 64 + lane];
    }
    #pragma unroll
    for (int u = 0; u < 8; ++u) { dd += wv[u]; acc += wv[u] * hv[u]; }
  }
  for (; j < cn; ++j) {
    int sj = __shfl(s0, j);
    float wj = __shfl(w0, j);
    dd += wj;
    acc += wj * h[(size_t)sj * 64 + lane];
  }
  for (int base = start + 64; base < end; base += 64) {
    int cnt = end - base; if (cnt > 64) cnt = 64;
    int st = 0; float u0 = 0.f;
    if (lane < cnt) {
      int e = perm[base + lane];
      st = src[e];
      u0 = __expf(leaky02(als[st] + ald0) - m0) * ew[e];
    }
    #pragma unroll 4
    for (int jj = 0; jj < cnt; ++jj) {
      int sj = __shfl(st, jj);
      float wj = __shfl(u0, jj);
      dd += wj;
      acc += wj * h[(size_t)sj * 64 + lane];
    }
  }

  float o = acc / (dd + 1e-16f) + bias[lane];
  if (RELU) o = fmaxf(o, 0.f);
  out[(size_t)node * 64 + lane] = o;
}

// ---------------- launch ----------------

extern "C" void kernel_launch(void* const* d_in, const int* in_sizes, int n_in,
                              void* d_out, int out_size, void* d_ws, size_t ws_size,
                              hipStream_t stream) {
  const int N = NNODES, E = NEDGES;
  const float* x   = (const float*)d_in[0];
  const int*   ei  = (const int*)d_in[1];
  const float* ew  = (const float*)d_in[2];
  const float* W1  = (const float*)d_in[3];
  const float* as1 = (const float*)d_in[4];
  const float* ad1 = (const float*)d_in[5];
  const float* b1  = (const float*)d_in[6];
  const float* W2  = (const float*)d_in[7];
  const float* as2 = (const float*)d_in[8];
  const float* ad2 = (const float*)d_in[9];
  const float* b2  = (const float*)d_in[10];
  const float* W3  = (const float*)d_in[11];
  const float* as3 = (const float*)d_in[12];
  const float* ad3 = (const float*)d_in[13];
  const float* b3  = (const float*)d_in[14];
  const int* src = ei;
  const int* dst = ei + E;

  uint8_t* p = (uint8_t*)d_ws;
  auto carve = [&](size_t bytes) {
    void* r = (void*)p;
    p += (bytes + 255) & ~(size_t)255;
    return r;
  };
  int*   counts  = (int*)carve((size_t)N * 4);
  int*   offsets = (int*)carve((size_t)(N + 1) * 4);
  int*   cursor  = (int*)carve((size_t)N * 4);
  int*   perm    = (int*)carve((size_t)E * 4);
  int*   bsums   = (int*)carve((size_t)256 * 4);
  float* als     = (float*)carve((size_t)N * 4 * 4);
  float* ald     = (float*)carve((size_t)N * 4 * 4);
  float* hA      = (float*)carve((size_t)N * 128 * 4);
  float* hB      = (float*)carve((size_t)N * 128 * 4);

  // CSR by dst (edge list is identical every call but must be rebuilt in-launch)
  int nb = (N + SCAN_CHUNK - 1) / SCAN_CHUNK;   // 49 <= 64
  hipMemsetAsync(counts, 0, (size_t)N * 4, stream);
  hist_kernel<<<(E + 255) / 256, 256, 0, stream>>>(dst, counts, E);
  scan_reduce_kernel<<<nb, 256, 0, stream>>>(counts, bsums, N);
  scan_spine_kernel<<<1, 64, 0, stream>>>(bsums, offsets, nb, N);
  scan_write_kernel<<<nb, 256, 0, stream>>>(counts, bsums, offsets, cursor, N);
  scatter_kernel<<<(E + 255) / 256, 256, 0, stream>>>(dst, cursor, perm, E);

  int aggGrid = (N + 3) / 4;

  // layer 1: [N,256] @ [256,128], H=4 C=32, relu
  gemm128_kernel<<<dim3((N + 127) / 128, 1), 256, 0, stream>>>(x, W1, hA, N, 256, 128);
  attnlog_kernel<4, 32><<<N, 128, 0, stream>>>(hA, as1, ad1, als, ald, N);
  aggregate4_kernel<true><<<aggGrid, 256, 0, stream>>>(hA, als, ald, ew, src, offsets,
                                                       perm, b1, hB, N);
  // layer 2: [N,128] @ [128,128], H=4 C=32, relu
  gemm128_kernel<<<dim3((N + 127) / 128, 1), 256, 0, stream>>>(hB, W2, hA, N, 128, 128);
  attnlog_kernel<4, 32><<<N, 128, 0, stream>>>(hA, as2, ad2, als, ald, N);
  aggregate4_kernel<true><<<aggGrid, 256, 0, stream>>>(hA, als, ald, ew, src, offsets,
                                                       perm, b2, hB, N);
  // layer 3: [N,128] @ [128,64], H=1 C=64, no relu, output fp32
  gemm_kernel<<<dim3((N + 63) / 64, 1), 256, 0, stream>>>(hB, W3, hA, N, 128, 64);
  attnlog_kernel<1, 64><<<N, 64, 0, stream>>>(hA, as3, ad3, als, ald, N);
  aggregate1_kernel<false><<<aggGrid, 256, 0, stream>>>(hA, als, ald, ew, src, offsets,
                                                        perm, b3, (float*)d_out, N);
}

// Round 5
// 518.431 us; speedup vs baseline: 1.7050x; 1.0850x over previous
//
#include <hip/hip_runtime.h>
#include <hip/hip_bf16.h>
#include <math.h>

#define NNODES 50000
#define NEDGES 800000
#define SCAN_CHUNK 1024   // elements per block in the multi-block scan

// bf16 <-> f32 helpers (bit-level, round-to-nearest-even)
__device__ __forceinline__ float bf2f(unsigned short u) {
  union { unsigned int i; float f; } c; c.i = ((unsigned int)u) << 16; return c.f;
}
__device__ __forceinline__ unsigned short f2bf(float f) {
  union { float f; unsigned int i; } c; c.f = f;
  unsigned int r = (c.i + 0x7FFFu + ((c.i >> 16) & 1u)) >> 16;
  return (unsigned short)r;
}

// ---------------- CSR build (sort edges by dst) ----------------

__global__ __launch_bounds__(256) void hist_kernel(const int* __restrict__ dst,
                                                   int* __restrict__ counts, int ne) {
  int i = blockIdx.x * blockDim.x + threadIdx.x;
  if (i < ne) atomicAdd(&counts[dst[i]], 1);
}

__global__ __launch_bounds__(256) void scan_reduce_kernel(const int* __restrict__ counts,
                                                          int* __restrict__ blockSums, int n) {
  int tid = threadIdx.x;
  int base = blockIdx.x * SCAN_CHUNK;
  int sum = 0;
  #pragma unroll
  for (int k = 0; k < SCAN_CHUNK / 256; ++k) {
    int i = base + k * 256 + tid;
    if (i < n) sum += counts[i];
  }
  #pragma unroll
  for (int o = 32; o > 0; o >>= 1) sum += __shfl_xor(sum, o);
  __shared__ int ws[4];
  if ((tid & 63) == 0) ws[tid >> 6] = sum;
  __syncthreads();
  if (tid == 0) blockSums[blockIdx.x] = ws[0] + ws[1] + ws[2] + ws[3];
}

__global__ __launch_bounds__(64) void scan_spine_kernel(int* __restrict__ blockSums,
                                                        int* __restrict__ offsets,
                                                        int nb, int n) {
  int tid = threadIdx.x;
  int v = (tid < nb) ? blockSums[tid] : 0;
  int incl = v;
  #pragma unroll
  for (int o = 1; o < 64; o <<= 1) {
    int u = __shfl_up(incl, o, 64);
    if (tid >= o) incl += u;
  }
  if (tid < nb) blockSums[tid] = incl - v;
  if (tid == 63) offsets[n] = incl;
}

__global__ __launch_bounds__(256) void scan_write_kernel(const int* __restrict__ counts,
                                                         const int* __restrict__ blockSums,
                                                         int* __restrict__ offsets,
                                                         int* __restrict__ cursor, int n) {
  int tid = threadIdx.x;
  int base = blockIdx.x * SCAN_CHUNK;
  int i0 = base + tid * 4;
  int4 c = make_int4(0, 0, 0, 0);
  if (i0 + 3 < n) c = *(const int4*)&counts[i0];
  else {
    if (i0 + 0 < n) c.x = counts[i0 + 0];
    if (i0 + 1 < n) c.y = counts[i0 + 1];
    if (i0 + 2 < n) c.z = counts[i0 + 2];
    if (i0 + 3 < n) c.w = counts[i0 + 3];
  }
  int s = c.x + c.y + c.z + c.w;
  int lane = tid & 63, wid = tid >> 6;
  int incl = s;
  #pragma unroll
  for (int o = 1; o < 64; o <<= 1) {
    int u = __shfl_up(incl, o, 64);
    if (lane >= o) incl += u;
  }
  __shared__ int ws[4];
  if (lane == 63) ws[wid] = incl;
  __syncthreads();
  if (tid == 0) {
    int a = 0;
    #pragma unroll
    for (int w = 0; w < 4; ++w) { int t = ws[w]; ws[w] = a; a += t; }
  }
  __syncthreads();
  int run = blockSums[blockIdx.x] + ws[wid] + (incl - s);
  if (i0 + 0 < n) { offsets[i0 + 0] = run; cursor[i0 + 0] = run; run += c.x; }
  if (i0 + 1 < n) { offsets[i0 + 1] = run; cursor[i0 + 1] = run; run += c.y; }
  if (i0 + 2 < n) { offsets[i0 + 2] = run; cursor[i0 + 2] = run; run += c.z; }
  if (i0 + 3 < n) { offsets[i0 + 3] = run; cursor[i0 + 3] = run; run += c.w; }
}

__global__ __launch_bounds__(256) void scatter_kernel(const int* __restrict__ dst,
                                                      int* __restrict__ cursor,
                                                      int* __restrict__ perm, int ne) {
  int i = blockIdx.x * blockDim.x + threadIdx.x;
  if (i < ne) {
    int pos = atomicAdd(&cursor[dst[i]], 1);
    perm[pos] = i;
  }
}

// ---------------- fp32 GEMM 128x128 tile + bf16 dual-store epilogue ---------

__global__ __launch_bounds__(256) void gemm128_kernel(const float* __restrict__ A,
                                                      const float* __restrict__ B,
                                                      float* __restrict__ C,
                                                      unsigned short* __restrict__ C16,
                                                      int M, int K, int D) {
  __shared__ float AsT[16][128];  // [k][row]
  __shared__ float Bs[16][128];   // [k][col]
  int tid = threadIdx.x;
  int tx = tid & 15, ty = tid >> 4;
  int row0 = blockIdx.x * 128, col0 = blockIdx.y * 128;
  float acc[2][2][4][4] = {};

  int arow = tid >> 1;
  int acg  = (tid & 1) * 8;
  int brow = tid >> 4;
  int bcg  = (tid & 15) * 4;
  int grow = row0 + arow;

  for (int k0 = 0; k0 < K; k0 += 16) {
    float4 av0, av1, bv0, bv1;
    if (grow < M) {
      av0 = *(const float4*)&A[(size_t)grow * K + k0 + acg];
      av1 = *(const float4*)&A[(size_t)grow * K + k0 + acg + 4];
    } else {
      av0 = make_float4(0.f, 0.f, 0.f, 0.f);
      av1 = av0;
    }
    bv0 = *(const float4*)&B[(size_t)(k0 + brow) * D + col0 + bcg];
    bv1 = *(const float4*)&B[(size_t)(k0 + brow) * D + col0 + 64 + bcg];
    __syncthreads();
    AsT[acg + 0][arow] = av0.x;
    AsT[acg + 1][arow] = av0.y;
    AsT[acg + 2][arow] = av0.z;
    AsT[acg + 3][arow] = av0.w;
    AsT[acg + 4][arow] = av1.x;
    AsT[acg + 5][arow] = av1.y;
    AsT[acg + 6][arow] = av1.z;
    AsT[acg + 7][arow] = av1.w;
    *(float4*)&Bs[brow][bcg] = bv0;
    *(float4*)&Bs[brow][64 + bcg] = bv1;
    __syncthreads();
    #pragma unroll
    for (int k = 0; k < 16; ++k) {
      float4 a0 = *(const float4*)&AsT[k][ty * 4];
      float4 a1 = *(const float4*)&AsT[k][64 + ty * 4];
      float4 b0 = *(const float4*)&Bs[k][tx * 4];
      float4 b1 = *(const float4*)&Bs[k][64 + tx * 4];
      float ar[2][4] = {{a0.x, a0.y, a0.z, a0.w}, {a1.x, a1.y, a1.z, a1.w}};
      float br[2][4] = {{b0.x, b0.y, b0.z, b0.w}, {b1.x, b1.y, b1.z, b1.w}};
      #pragma unroll
      for (int rh = 0; rh < 2; ++rh)
        #pragma unroll
        for (int ch = 0; ch < 2; ++ch)
          #pragma unroll
          for (int i = 0; i < 4; ++i)
            #pragma unroll
            for (int j = 0; j < 4; ++j)
              acc[rh][ch][i][j] += ar[rh][i] * br[ch][j];
    }
  }
  #pragma unroll
  for (int rh = 0; rh < 2; ++rh)
    #pragma unroll
    for (int i = 0; i < 4; ++i) {
      int r = row0 + rh * 64 + ty * 4 + i;
      if (r < M) {
        #pragma unroll
        for (int ch = 0; ch < 2; ++ch) {
          size_t cidx = (size_t)r * D + col0 + ch * 64 + tx * 4;
          *(float4*)&C[cidx] = make_float4(acc[rh][ch][i][0], acc[rh][ch][i][1],
                                           acc[rh][ch][i][2], acc[rh][ch][i][3]);
          unsigned short b16[4] = {f2bf(acc[rh][ch][i][0]), f2bf(acc[rh][ch][i][1]),
                                   f2bf(acc[rh][ch][i][2]), f2bf(acc[rh][ch][i][3])};
          *(ushort4*)&C16[cidx] = *(ushort4*)b16;
        }
      }
    }
}

// ---------------- fp32 tiled GEMM 64x64 + bf16 dual-store (layer 3) ---------

__global__ __launch_bounds__(256) void gemm_kernel(const float* __restrict__ A,
                                                   const float* __restrict__ B,
                                                   float* __restrict__ C,
                                                   unsigned short* __restrict__ C16,
                                                   int M, int K, int D) {
  __shared__ float AsT[16][64];
  __shared__ float Bs[16][64];
  int tid = threadIdx.x;
  int tx = tid & 15, ty = tid >> 4;
  int row0 = blockIdx.x * 64, col0 = blockIdx.y * 64;
  float acc[4][4] = {};

  int arow = tid >> 2;
  int acg  = (tid & 3) * 4;
  int brow = tid >> 4;
  int bcg  = (tid & 15) * 4;
  int grow = row0 + arow;

  for (int k0 = 0; k0 < K; k0 += 16) {
    float4 av;
    if (grow < M) av = *(const float4*)&A[(size_t)grow * K + k0 + acg];
    else          av = make_float4(0.f, 0.f, 0.f, 0.f);
    float4 bv = *(const float4*)&B[(size_t)(k0 + brow) * D + col0 + bcg];
    __syncthreads();
    AsT[acg + 0][arow] = av.x;
    AsT[acg + 1][arow] = av.y;
    AsT[acg + 2][arow] = av.z;
    AsT[acg + 3][arow] = av.w;
    *(float4*)&Bs[brow][bcg] = bv;
    __syncthreads();
    #pragma unroll
    for (int k = 0; k < 16; ++k) {
      float4 a4 = *(const float4*)&AsT[k][ty * 4];
      float4 b4 = *(const float4*)&Bs[k][tx * 4];
      float a[4] = {a4.x, a4.y, a4.z, a4.w};
      float b[4] = {b4.x, b4.y, b4.z, b4.w};
      #pragma unroll
      for (int i = 0; i < 4; ++i)
        #pragma unroll
        for (int j = 0; j < 4; ++j)
          acc[i][j] += a[i] * b[j];
    }
  }
  #pragma unroll
  for (int i = 0; i < 4; ++i) {
    int r = row0 + ty * 4 + i;
    if (r < M) {
      size_t cidx = (size_t)r * D + col0 + tx * 4;
      *(float4*)&C[cidx] = make_float4(acc[i][0], acc[i][1], acc[i][2], acc[i][3]);
      unsigned short b16[4] = {f2bf(acc[i][0]), f2bf(acc[i][1]),
                               f2bf(acc[i][2]), f2bf(acc[i][3])};
      *(ushort4*)&C16[cidx] = *(ushort4*)b16;
    }
  }
}

// ---------------- per-node attention logits: als/ald [N,H] ----------------

template<int H, int C>
__global__ __launch_bounds__(128) void attnlog_kernel(const float* __restrict__ h,
                                                      const float* __restrict__ a_src,
                                                      const float* __restrict__ a_dst,
                                                      float* __restrict__ als,
                                                      float* __restrict__ ald, int n_nodes) {
  constexpr int D = H * C;
  int n = blockIdx.x;
  int t = threadIdx.x;
  float hv = h[(size_t)n * D + t];
  float s = hv * a_src[t];
  float d = hv * a_dst[t];
  #pragma unroll
  for (int o = C / 2; o > 0; o >>= 1) {
    s += __shfl_xor(s, o, C);
    d += __shfl_xor(d, o, C);
  }
  if ((t & (C - 1)) == 0) {
    als[n * H + t / C] = s;
    ald[n * H + t / C] = d;
  }
}

// ---------------- per-dst-node softmax + weighted aggregation ----------------
// bf16 h gather table: agg4 reads ONE ushort2 (2 channels) per lane per edge
// (256 B/row, half the fp32 traffic, single load). Lane l covers channels
// {2l, 2l+1}, both in head l>>4. All softmax math stays fp32.

__device__ __forceinline__ float leaky02(float v) { return v > 0.f ? v : 0.2f * v; }

template<bool RELU>
__global__ __launch_bounds__(256) void aggregate4_kernel(const unsigned short* __restrict__ h16,
                                                         const float* __restrict__ als,
                                                         const float* __restrict__ ald,
                                                         const float* __restrict__ ew,
                                                         const int* __restrict__ src,
                                                         const int* __restrict__ offsets,
                                                         const int* __restrict__ perm,
                                                         const float* __restrict__ bias,
                                                         float* __restrict__ out, int n_nodes) {
  int node = blockIdx.x * (blockDim.x >> 6) + (threadIdx.x >> 6);
  int lane = threadIdx.x & 63;
  if (node >= n_nodes) return;
  int start = offsets[node], end = offsets[node + 1];
  int deg = end - start;

  float4 aldv = *(const float4*)&ald[node * 4];

  // stage first chunk (covers deg <= 64: ~always for Poisson(16))
  int s0 = 0; float wgt0 = 0.f;
  float v0 = 0.f, v1 = 0.f, v2 = 0.f, v3 = 0.f;
  float m0 = -INFINITY, m1 = -INFINITY, m2 = -INFINITY, m3 = -INFINITY;
  if (lane < deg) {
    int e = perm[start + lane];
    s0 = src[e];
    wgt0 = ew[e];
    float4 a4 = *(const float4*)&als[s0 * 4];
    v0 = leaky02(a4.x + aldv.x); m0 = v0;
    v1 = leaky02(a4.y + aldv.y); m1 = v1;
    v2 = leaky02(a4.z + aldv.z); m2 = v2;
    v3 = leaky02(a4.w + aldv.w); m3 = v3;
  }
  for (int j = start + 64 + lane; j < end; j += 64) {
    int e = perm[j];
    int s = src[e];
    float4 a4 = *(const float4*)&als[s * 4];
    m0 = fmaxf(m0, leaky02(a4.x + aldv.x));
    m1 = fmaxf(m1, leaky02(a4.y + aldv.y));
    m2 = fmaxf(m2, leaky02(a4.z + aldv.z));
    m3 = fmaxf(m3, leaky02(a4.w + aldv.w));
  }
  #pragma unroll
  for (int o = 32; o > 0; o >>= 1) {
    m0 = fmaxf(m0, __shfl_xor(m0, o));
    m1 = fmaxf(m1, __shfl_xor(m1, o));
    m2 = fmaxf(m2, __shfl_xor(m2, o));
    m3 = fmaxf(m3, __shfl_xor(m3, o));
  }

  float w0 = 0.f, w1 = 0.f, w2 = 0.f, w3 = 0.f;
  if (lane < deg) {
    w0 = __expf(v0 - m0) * wgt0;
    w1 = __expf(v1 - m1) * wgt0;
    w2 = __expf(v2 - m2) * wgt0;
    w3 = __expf(v3 - m3) * wgt0;
  }

  int head = lane >> 4;           // this lane's channels 2l,2l+1 are in this head
  float accX = 0.f, accY = 0.f, dd = 0.f;
  int cn = deg < 64 ? deg : 64;
  int j = 0;
  for (; j + 8 <= cn; j += 8) {
    float hx[8], hy[8], wj[8];
    #pragma unroll
    for (int u = 0; u < 8; ++u) {
      int sj = __shfl(s0, j + u);
      float t0 = __shfl(w0, j + u), t1 = __shfl(w1, j + u);
      float t2 = __shfl(w2, j + u), t3 = __shfl(w3, j + u);
      float wa = head == 0 ? t0 : head == 1 ? t1 : head == 2 ? t2 : t3;
      wj[u] = wa;
      ushort2 hv = *(const ushort2*)&h16[(size_t)sj * 128 + 2 * lane];
      hx[u] = bf2f(hv.x);
      hy[u] = bf2f(hv.y);
    }
    #pragma unroll
    for (int u = 0; u < 8; ++u) {
      dd += wj[u];
      accX += wj[u] * hx[u];
      accY += wj[u] * hy[u];
    }
  }
  for (; j < cn; ++j) {
    int sj = __shfl(s0, j);
    float t0 = __shfl(w0, j), t1 = __shfl(w1, j);
    float t2 = __shfl(w2, j), t3 = __shfl(w3, j);
    float wa = head == 0 ? t0 : head == 1 ? t1 : head == 2 ? t2 : t3;
    ushort2 hv = *(const ushort2*)&h16[(size_t)sj * 128 + 2 * lane];
    dd += wa;
    accX += wa * bf2f(hv.x);
    accY += wa * bf2f(hv.y);
  }
  // rare tail: deg > 64
  for (int base = start + 64; base < end; base += 64) {
    int cnt = end - base; if (cnt > 64) cnt = 64;
    int st = 0; float u0 = 0.f, u1 = 0.f, u2 = 0.f, u3 = 0.f;
    if (lane < cnt) {
      int e = perm[base + lane];
      st = src[e];
      float wg = ew[e];
      float4 a4 = *(const float4*)&als[st * 4];
      u0 = __expf(leaky02(a4.x + aldv.x) - m0) * wg;
      u1 = __expf(leaky02(a4.y + aldv.y) - m1) * wg;
      u2 = __expf(leaky02(a4.z + aldv.z) - m2) * wg;
      u3 = __expf(leaky02(a4.w + aldv.w) - m3) * wg;
    }
    for (int jj = 0; jj < cnt; ++jj) {
      int sj = __shfl(st, jj);
      float t0 = __shfl(u0, jj), t1 = __shfl(u1, jj);
      float t2 = __shfl(u2, jj), t3 = __shfl(u3, jj);
      float wa = head == 0 ? t0 : head == 1 ? t1 : head == 2 ? t2 : t3;
      ushort2 hv = *(const ushort2*)&h16[(size_t)sj * 128 + 2 * lane];
      dd += wa;
      accX += wa * bf2f(hv.x);
      accY += wa * bf2f(hv.y);
    }
  }

  float inv = 1.f / (dd + 1e-16f);
  float oX = accX * inv + bias[2 * lane];
  float oY = accY * inv + bias[2 * lane + 1];
  if (RELU) { oX = fmaxf(oX, 0.f); oY = fmaxf(oY, 0.f); }
  *(float2*)&out[(size_t)node * 128 + 2 * lane] = make_float2(oX, oY);
}

// H == 1, C == 64 variant (layer 3): lane loads one bf16 channel per edge.
template<bool RELU>
__global__ __launch_bounds__(256) void aggregate1_kernel(const unsigned short* __restrict__ h16,
                                                         const float* __restrict__ als,
                                                         const float* __restrict__ ald,
                                                         const float* __restrict__ ew,
                                                         const int* __restrict__ src,
                                                         const int* __restrict__ offsets,
                                                         const int* __restrict__ perm,
                                                         const float* __restrict__ bias,
                                                         float* __restrict__ out, int n_nodes) {
  int node = blockIdx.x * (blockDim.x >> 6) + (threadIdx.x >> 6);
  int lane = threadIdx.x & 63;
  if (node >= n_nodes) return;
  int start = offsets[node], end = offsets[node + 1];
  int deg = end - start;

  float ald0 = ald[node];
  int s0 = 0; float wgt0 = 0.f, v0 = 0.f, m0 = -INFINITY;
  if (lane < deg) {
    int e = perm[start + lane];
    s0 = src[e];
    wgt0 = ew[e];
    v0 = leaky02(als[s0] + ald0);
    m0 = v0;
  }
  for (int j = start + 64 + lane; j < end; j += 64) {
    int e = perm[j];
    int s = src[e];
    m0 = fmaxf(m0, leaky02(als[s] + ald0));
  }
  #pragma unroll
  for (int o = 32; o > 0; o >>= 1) m0 = fmaxf(m0, __shfl_xor(m0, o));

  float w0 = (lane < deg) ? __expf(v0 - m0) * wgt0 : 0.f;

  float acc = 0.f, dd = 0.f;
  int cn = deg < 64 ? deg : 64;
  int j = 0;
  for (; j + 8 <= cn; j += 8) {
    float hv[8], wv[8];
    #pragma unroll
    for (int u = 0; u < 8; ++u) {
      int sj = __shfl(s0, j + u);
      wv[u] = __shfl(w0, j + u);
      hv[u] = bf2f(h16[(size_t)sj * 64 + lane]);
    }
    #pragma unroll
    for (int u = 0; u < 8; ++u) { dd += wv[u]; acc += wv[u] * hv[u]; }
  }
  for (; j < cn; ++j) {
    int sj = __shfl(s0, j);
    float wj = __shfl(w0, j);
    dd += wj;
    acc += wj * bf2f(h16[(size_t)sj * 64 + lane]);
  }
  for (int base = start + 64; base < end; base += 64) {
    int cnt = end - base; if (cnt > 64) cnt = 64;
    int st = 0; float u0 = 0.f;
    if (lane < cnt) {
      int e = perm[base + lane];
      st = src[e];
      u0 = __expf(leaky02(als[st] + ald0) - m0) * ew[e];
    }
    for (int jj = 0; jj < cnt; ++jj) {
      int sj = __shfl(st, jj);
      float wj = __shfl(u0, jj);
      dd += wj;
      acc += wj * bf2f(h16[(size_t)sj * 64 + lane]);
    }
  }

  float o = acc / (dd + 1e-16f) + bias[lane];
  if (RELU) o = fmaxf(o, 0.f);
  out[(size_t)node * 64 + lane] = o;
}

// ---------------- launch ----------------

extern "C" void kernel_launch(void* const* d_in, const int* in_sizes, int n_in,
                              void* d_out, int out_size, void* d_ws, size_t ws_size,
                              hipStream_t stream) {
  const int N = NNODES, E = NEDGES;
  const float* x   = (const float*)d_in[0];
  const int*   ei  = (const int*)d_in[1];
  const float* ew  = (const float*)d_in[2];
  const float* W1  = (const float*)d_in[3];
  const float* as1 = (const float*)d_in[4];
  const float* ad1 = (const float*)d_in[5];
  const float* b1  = (const float*)d_in[6];
  const float* W2  = (const float*)d_in[7];
  const float* as2 = (const float*)d_in[8];
  const float* ad2 = (const float*)d_in[9];
  const float* b2  = (const float*)d_in[10];
  const float* W3  = (const float*)d_in[11];
  const float* as3 = (const float*)d_in[12];
  const float* ad3 = (const float*)d_in[13];
  const float* b3  = (const float*)d_in[14];
  const int* src = ei;
  const int* dst = ei + E;

  uint8_t* p = (uint8_t*)d_ws;
  auto carve = [&](size_t bytes) {
    void* r = (void*)p;
    p += (bytes + 255) & ~(size_t)255;
    return r;
  };
  int*   counts  = (int*)carve((size_t)N * 4);
  int*   offsets = (int*)carve((size_t)(N + 1) * 4);
  int*   cursor  = (int*)carve((size_t)N * 4);
  int*   perm    = (int*)carve((size_t)E * 4);
  int*   bsums   = (int*)carve((size_t)256 * 4);
  float* als     = (float*)carve((size_t)N * 4 * 4);
  float* ald     = (float*)carve((size_t)N * 4 * 4);
  float* hA      = (float*)carve((size_t)N * 128 * 4);
  float* hB      = (float*)carve((size_t)N * 128 * 4);
  unsigned short* h16 = (unsigned short*)carve((size_t)N * 128 * 2);

  // CSR by dst (edge list is identical every call but must be rebuilt in-launch)
  int nb = (N + SCAN_CHUNK - 1) / SCAN_CHUNK;   // 49 <= 64
  hipMemsetAsync(counts, 0, (size_t)N * 4, stream);
  hist_kernel<<<(E + 255) / 256, 256, 0, stream>>>(dst, counts, E);
  scan_reduce_kernel<<<nb, 256, 0, stream>>>(counts, bsums, N);
  scan_spine_kernel<<<1, 64, 0, stream>>>(bsums, offsets, nb, N);
  scan_write_kernel<<<nb, 256, 0, stream>>>(counts, bsums, offsets, cursor, N);
  scatter_kernel<<<(E + 255) / 256, 256, 0, stream>>>(dst, cursor, perm, E);

  int aggGrid = (N + 3) / 4;

  // layer 1: [N,256] @ [256,128], H=4 C=32, relu
  gemm128_kernel<<<dim3((N + 127) / 128, 1), 256, 0, stream>>>(x, W1, hA, h16, N, 256, 128);
  attnlog_kernel<4, 32><<<N, 128, 0, stream>>>(hA, as1, ad1, als, ald, N);
  aggregate4_kernel<true><<<aggGrid, 256, 0, stream>>>(h16, als, ald, ew, src, offsets,
                                                       perm, b1, hB, N);
  // layer 2: [N,128] @ [128,128], H=4 C=32, relu
  gemm128_kernel<<<dim3((N + 127) / 128, 1), 256, 0, stream>>>(hB, W2, hA, h16, N, 128, 128);
  attnlog_kernel<4, 32><<<N, 128, 0, stream>>>(hA, as2, ad2, als, ald, N);
  aggregate4_kernel<true><<<aggGrid, 256, 0, stream>>>(h16, als, ald, ew, src, offsets,
                                                       perm, b2, hB, N);
  // layer 3: [N,128] @ [128,64], H=1 C=64, no relu, output fp32
  gemm_kernel<<<dim3((N + 63) / 64, 1), 256, 0, stream>>>(hB, W3, hA, h16, N, 128, 64);
  attnlog_kernel<1, 64><<<N, 64, 0, stream>>>(hA, as3, ad3, als, ald, N);
  aggregate1_kernel<false><<<aggGrid, 256, 0, stream>>>(h16, als, ald, ew, src, offsets,
                                                        perm, b3, (float*)d_out, N);
}

// Round 6
// 441.704 us; speedup vs baseline: 2.0012x; 1.1737x over previous
//
#include <hip/hip_runtime.h>
#include <math.h>

#define NNODES 50000
#define NEDGES 800000
#define SCAN_CHUNK 1024

typedef _Float16 f16;
typedef __attribute__((ext_vector_type(2))) _Float16 f16x2;
typedef __attribute__((ext_vector_type(4))) _Float16 f16x4;
typedef __attribute__((ext_vector_type(8))) _Float16 f16x8;
typedef __attribute__((ext_vector_type(4))) float f32x4;

// ---------------- CSR build (sort edges by dst) ----------------

__global__ __launch_bounds__(256) void hist_kernel(const int* __restrict__ dst,
                                                   int* __restrict__ counts, int ne) {
  int i = blockIdx.x * blockDim.x + threadIdx.x;
  if (i < ne) atomicAdd(&counts[dst[i]], 1);
}

__global__ __launch_bounds__(256) void scan_reduce_kernel(const int* __restrict__ counts,
                                                          int* __restrict__ blockSums, int n) {
  int tid = threadIdx.x;
  int base = blockIdx.x * SCAN_CHUNK;
  int sum = 0;
  #pragma unroll
  for (int k = 0; k < SCAN_CHUNK / 256; ++k) {
    int i = base + k * 256 + tid;
    if (i < n) sum += counts[i];
  }
  #pragma unroll
  for (int o = 32; o > 0; o >>= 1) sum += __shfl_xor(sum, o);
  __shared__ int ws[4];
  if ((tid & 63) == 0) ws[tid >> 6] = sum;
  __syncthreads();
  if (tid == 0) blockSums[blockIdx.x] = ws[0] + ws[1] + ws[2] + ws[3];
}

__global__ __launch_bounds__(64) void scan_spine_kernel(int* __restrict__ blockSums,
                                                        int* __restrict__ offsets,
                                                        int nb, int n) {
  int tid = threadIdx.x;
  int v = (tid < nb) ? blockSums[tid] : 0;
  int incl = v;
  #pragma unroll
  for (int o = 1; o < 64; o <<= 1) {
    int u = __shfl_up(incl, o, 64);
    if (tid >= o) incl += u;
  }
  if (tid < nb) blockSums[tid] = incl - v;
  if (tid == 63) offsets[n] = incl;
}

__global__ __launch_bounds__(256) void scan_write_kernel(const int* __restrict__ counts,
                                                         const int* __restrict__ blockSums,
                                                         int* __restrict__ offsets,
                                                         int* __restrict__ cursor, int n) {
  int tid = threadIdx.x;
  int base = blockIdx.x * SCAN_CHUNK;
  int i0 = base + tid * 4;
  int4 c = make_int4(0, 0, 0, 0);
  if (i0 + 3 < n) c = *(const int4*)&counts[i0];
  else {
    if (i0 + 0 < n) c.x = counts[i0 + 0];
    if (i0 + 1 < n) c.y = counts[i0 + 1];
    if (i0 + 2 < n) c.z = counts[i0 + 2];
    if (i0 + 3 < n) c.w = counts[i0 + 3];
  }
  int s = c.x + c.y + c.z + c.w;
  int lane = tid & 63, wid = tid >> 6;
  int incl = s;
  #pragma unroll
  for (int o = 1; o < 64; o <<= 1) {
    int u = __shfl_up(incl, o, 64);
    if (lane >= o) incl += u;
  }
  __shared__ int ws[4];
  if (lane == 63) ws[wid] = incl;
  __syncthreads();
  if (tid == 0) {
    int a = 0;
    #pragma unroll
    for (int w = 0; w < 4; ++w) { int t = ws[w]; ws[w] = a; a += t; }
  }
  __syncthreads();
  int run = blockSums[blockIdx.x] + ws[wid] + (incl - s);
  if (i0 + 0 < n) { offsets[i0 + 0] = run; cursor[i0 + 0] = run; run += c.x; }
  if (i0 + 1 < n) { offsets[i0 + 1] = run; cursor[i0 + 1] = run; run += c.y; }
  if (i0 + 2 < n) { offsets[i0 + 2] = run; cursor[i0 + 2] = run; run += c.z; }
  if (i0 + 3 < n) { offsets[i0 + 3] = run; cursor[i0 + 3] = run; run += c.w; }
}

__global__ __launch_bounds__(256) void scatter_kernel(const int* __restrict__ dst,
                                                      int* __restrict__ cursor,
                                                      int* __restrict__ perm, int ne) {
  int i = blockIdx.x * blockDim.x + threadIdx.x;
  if (i < ne) {
    int pos = atomicAdd(&cursor[dst[i]], 1);
    perm[pos] = i;
  }
}

// ---------------- weight prep: W[k][d] fp32 -> WT[d][k] fp16 ----------------

__global__ __launch_bounds__(256) void prepw_kernel(const float* __restrict__ W1,
                                                    const float* __restrict__ W2,
                                                    const float* __restrict__ W3,
                                                    f16* __restrict__ WT1,
                                                    f16* __restrict__ WT2,
                                                    f16* __restrict__ WT3) {
  int idx = blockIdx.x * 256 + threadIdx.x;
  if (idx < 32768) {                       // W1: K=256, D=128
    int d = idx >> 8, k = idx & 255;
    WT1[idx] = (f16)W1[k * 128 + d];
  } else if (idx < 49152) {                // W2: K=128, D=128
    int j = idx - 32768;
    int d = j >> 7, k = j & 127;
    WT2[j] = (f16)W2[k * 128 + d];
  } else if (idx < 57344) {                // W3: K=128, D=64
    int j = idx - 49152;
    int d = j >> 7, k = j & 127;
    WT3[j] = (f16)W3[k * 64 + d];
  }
}

// ---------------- fp16 MFMA GEMM: C[M,BN] = A[M,K] @ B[K,BN] ----------------
// BM=64, BK=64, BN == D (block covers all columns). 4 waves in 2x2; each wave
// computes 32 x BN/2 via 16x16x32 f16 MFMA, fp32 accumulate.
// BT is the pre-transposed fp16 weight [BN][K]. AT = float (convert in
// staging) or _Float16 (direct). Verified layouts: A-frag A[m=lane&15]
// [k=quad*8+j]; B-frag B[k=quad*8+j][n=lane&15]; C/D col=lane&15,row=quad*4+v.

template<typename AT, int BN>
__global__ __launch_bounds__(256) void gemm_mfma_kernel(const AT* __restrict__ A,
                                                        const f16* __restrict__ BT,
                                                        f16* __restrict__ C,
                                                        int M, int K) {
  constexpr int BM = 64;
  constexpr int WN = BN / 2;
  constexpr int MT = 2, NT = WN / 16;
  __shared__ f16 As[BM * 72];
  __shared__ f16 Bs[BN * 72];
  int tid = threadIdx.x;
  int lane = tid & 63, wave = tid >> 6;
  int wm = wave & 1, wn = wave >> 1;
  int row0 = blockIdx.x * BM;
  int quad = lane >> 4, cc = lane & 15;

  f32x4 acc[MT][NT];
  #pragma unroll
  for (int mt = 0; mt < MT; ++mt)
    #pragma unroll
    for (int nt = 0; nt < NT; ++nt)
      acc[mt][nt] = (f32x4){0.f, 0.f, 0.f, 0.f};

  for (int k0 = 0; k0 < K; k0 += 64) {
    __syncthreads();
    if constexpr (sizeof(AT) == 4) {
      #pragma unroll
      for (int i = 0; i < 4; ++i) {
        int r = i * 16 + (tid >> 4);
        int kc = (tid & 15) * 4;
        float4 av = make_float4(0.f, 0.f, 0.f, 0.f);
        if (row0 + r < M) av = *(const float4*)&A[(size_t)(row0 + r) * K + k0 + kc];
        *(f16x4*)&As[r * 72 + kc] = (f16x4){(f16)av.x, (f16)av.y, (f16)av.z, (f16)av.w};
      }
    } else {
      #pragma unroll
      for (int i = 0; i < 2; ++i) {
        int r = i * 32 + (tid >> 3);
        int kc = (tid & 7) * 8;
        f16x8 hv = {0, 0, 0, 0, 0, 0, 0, 0};
        if (row0 + r < M) hv = *(const f16x8*)&A[(size_t)(row0 + r) * K + k0 + kc];
        *(f16x8*)&As[r * 72 + kc] = hv;
      }
    }
    #pragma unroll
    for (int i = 0; i < BN / 32; ++i) {
      int d = i * 32 + (tid >> 3);
      int kc = (tid & 7) * 8;
      *(f16x8*)&Bs[d * 72 + kc] = *(const f16x8*)&BT[(size_t)d * K + k0 + kc];
    }
    __syncthreads();
    #pragma unroll
    for (int ki = 0; ki < 2; ++ki) {
      f16x8 a[MT], b[NT];
      #pragma unroll
      for (int mt = 0; mt < MT; ++mt)
        a[mt] = *(const f16x8*)&As[(wm * 32 + mt * 16 + cc) * 72 + ki * 32 + quad * 8];
      #pragma unroll
      for (int nt = 0; nt < NT; ++nt)
        b[nt] = *(const f16x8*)&Bs[(wn * WN + nt * 16 + cc) * 72 + ki * 32 + quad * 8];
      #pragma unroll
      for (int mt = 0; mt < MT; ++mt)
        #pragma unroll
        for (int nt = 0; nt < NT; ++nt)
          acc[mt][nt] = __builtin_amdgcn_mfma_f32_16x16x32_f16(a[mt], b[nt], acc[mt][nt], 0, 0, 0);
    }
  }

  #pragma unroll
  for (int mt = 0; mt < MT; ++mt)
    #pragma unroll
    for (int v = 0; v < 4; ++v) {
      int row = row0 + wm * 32 + mt * 16 + quad * 4 + v;
      if (row < M) {
        #pragma unroll
        for (int nt = 0; nt < NT; ++nt)
          C[(size_t)row * BN + wn * WN + nt * 16 + cc] = (f16)acc[mt][nt][v];
      }
    }
}

// ---------------- per-node attention logits: als/ald [N,H] ----------------

template<int H, int C>
__global__ __launch_bounds__(128) void attnlog_kernel(const f16* __restrict__ h,
                                                      const float* __restrict__ a_src,
                                                      const float* __restrict__ a_dst,
                                                      float* __restrict__ als,
                                                      float* __restrict__ ald, int n_nodes) {
  constexpr int D = H * C;
  int n = blockIdx.x;
  int t = threadIdx.x;
  float hv = (float)h[(size_t)n * D + t];
  float s = hv * a_src[t];
  float d = hv * a_dst[t];
  #pragma unroll
  for (int o = C / 2; o > 0; o >>= 1) {
    s += __shfl_xor(s, o, C);
    d += __shfl_xor(d, o, C);
  }
  if ((t & (C - 1)) == 0) {
    als[n * H + t / C] = s;
    ald[n * H + t / C] = d;
  }
}

// ---------------- per-dst-node softmax + weighted aggregation ----------------
// One wave per node; lane-parallel edge staging; unroll-by-8 gather batching.
// h table is fp16; agg4 writes fp16 (next GEMM's A input), agg1 writes fp32.

__device__ __forceinline__ float leaky02(float v) { return v > 0.f ? v : 0.2f * v; }

template<bool RELU>
__global__ __launch_bounds__(256) void aggregate4_kernel(const f16* __restrict__ h16,
                                                         const float* __restrict__ als,
                                                         const float* __restrict__ ald,
                                                         const float* __restrict__ ew,
                                                         const int* __restrict__ src,
                                                         const int* __restrict__ offsets,
                                                         const int* __restrict__ perm,
                                                         const float* __restrict__ bias,
                                                         f16* __restrict__ out, int n_nodes) {
  int node = blockIdx.x * (blockDim.x >> 6) + (threadIdx.x >> 6);
  int lane = threadIdx.x & 63;
  if (node >= n_nodes) return;
  int start = offsets[node], end = offsets[node + 1];
  int deg = end - start;

  float4 aldv = *(const float4*)&ald[node * 4];

  int s0 = 0; float wgt0 = 0.f;
  float v0 = 0.f, v1 = 0.f, v2 = 0.f, v3 = 0.f;
  float m0 = -INFINITY, m1 = -INFINITY, m2 = -INFINITY, m3 = -INFINITY;
  if (lane < deg) {
    int e = perm[start + lane];
    s0 = src[e];
    wgt0 = ew[e];
    float4 a4 = *(const float4*)&als[s0 * 4];
    v0 = leaky02(a4.x + aldv.x); m0 = v0;
    v1 = leaky02(a4.y + aldv.y); m1 = v1;
    v2 = leaky02(a4.z + aldv.z); m2 = v2;
    v3 = leaky02(a4.w + aldv.w); m3 = v3;
  }
  for (int j = start + 64 + lane; j < end; j += 64) {
    int e = perm[j];
    int s = src[e];
    float4 a4 = *(const float4*)&als[s * 4];
    m0 = fmaxf(m0, leaky02(a4.x + aldv.x));
    m1 = fmaxf(m1, leaky02(a4.y + aldv.y));
    m2 = fmaxf(m2, leaky02(a4.z + aldv.z));
    m3 = fmaxf(m3, leaky02(a4.w + aldv.w));
  }
  #pragma unroll
  for (int o = 32; o > 0; o >>= 1) {
    m0 = fmaxf(m0, __shfl_xor(m0, o));
    m1 = fmaxf(m1, __shfl_xor(m1, o));
    m2 = fmaxf(m2, __shfl_xor(m2, o));
    m3 = fmaxf(m3, __shfl_xor(m3, o));
  }

  float w0 = 0.f, w1 = 0.f, w2 = 0.f, w3 = 0.f;
  if (lane < deg) {
    w0 = __expf(v0 - m0) * wgt0;
    w1 = __expf(v1 - m1) * wgt0;
    w2 = __expf(v2 - m2) * wgt0;
    w3 = __expf(v3 - m3) * wgt0;
  }

  int head = lane >> 4;           // channels 2l,2l+1 belong to this head
  float accX = 0.f, accY = 0.f, dd = 0.f;
  int cn = deg < 64 ? deg : 64;
  int j = 0;
  for (; j + 8 <= cn; j += 8) {
    float hx[8], hy[8], wj[8];
    #pragma unroll
    for (int u = 0; u < 8; ++u) {
      int sj = __shfl(s0, j + u);
      float t0 = __shfl(w0, j + u), t1 = __shfl(w1, j + u);
      float t2 = __shfl(w2, j + u), t3 = __shfl(w3, j + u);
      wj[u] = head == 0 ? t0 : head == 1 ? t1 : head == 2 ? t2 : t3;
      f16x2 hv = *(const f16x2*)&h16[(size_t)sj * 128 + 2 * lane];
      hx[u] = (float)hv[0];
      hy[u] = (float)hv[1];
    }
    #pragma unroll
    for (int u = 0; u < 8; ++u) {
      dd += wj[u];
      accX += wj[u] * hx[u];
      accY += wj[u] * hy[u];
    }
  }
  for (; j < cn; ++j) {
    int sj = __shfl(s0, j);
    float t0 = __shfl(w0, j), t1 = __shfl(w1, j);
    float t2 = __shfl(w2, j), t3 = __shfl(w3, j);
    float wa = head == 0 ? t0 : head == 1 ? t1 : head == 2 ? t2 : t3;
    f16x2 hv = *(const f16x2*)&h16[(size_t)sj * 128 + 2 * lane];
    dd += wa;
    accX += wa * (float)hv[0];
    accY += wa * (float)hv[1];
  }
  for (int base = start + 64; base < end; base += 64) {
    int cnt = end - base; if (cnt > 64) cnt = 64;
    int st = 0; float u0 = 0.f, u1 = 0.f, u2 = 0.f, u3 = 0.f;
    if (lane < cnt) {
      int e = perm[base + lane];
      st = src[e];
      float wg = ew[e];
      float4 a4 = *(const float4*)&als[st * 4];
      u0 = __expf(leaky02(a4.x + aldv.x) - m0) * wg;
      u1 = __expf(leaky02(a4.y + aldv.y) - m1) * wg;
      u2 = __expf(leaky02(a4.z + aldv.z) - m2) * wg;
      u3 = __expf(leaky02(a4.w + aldv.w) - m3) * wg;
    }
    for (int jj = 0; jj < cnt; ++jj) {
      int sj = __shfl(st, jj);
      float t0 = __shfl(u0, jj), t1 = __shfl(u1, jj);
      float t2 = __shfl(u2, jj), t3 = __shfl(u3, jj);
      float wa = head == 0 ? t0 : head == 1 ? t1 : head == 2 ? t2 : t3;
      f16x2 hv = *(const f16x2*)&h16[(size_t)sj * 128 + 2 * lane];
      dd += wa;
      accX += wa * (float)hv[0];
      accY += wa * (float)hv[1];
    }
  }

  float inv = 1.f / (dd + 1e-16f);
  float oX = accX * inv + bias[2 * lane];
  float oY = accY * inv + bias[2 * lane + 1];
  if (RELU) { oX = fmaxf(oX, 0.f); oY = fmaxf(oY, 0.f); }
  *(f16x2*)&out[(size_t)node * 128 + 2 * lane] = (f16x2){(f16)oX, (f16)oY};
}

// H == 1, C == 64 variant (layer 3), fp32 output
template<bool RELU>
__global__ __launch_bounds__(256) void aggregate1_kernel(const f16* __restrict__ h16,
                                                         const float* __restrict__ als,
                                                         const float* __restrict__ ald,
                                                         const float* __restrict__ ew,
                                                         const int* __restrict__ src,
                                                         const int* __restrict__ offsets,
                                                         const int* __restrict__ perm,
                                                         const float* __restrict__ bias,
                                                         float* __restrict__ out, int n_nodes) {
  int node = blockIdx.x * (blockDim.x >> 6) + (threadIdx.x >> 6);
  int lane = threadIdx.x & 63;
  if (node >= n_nodes) return;
  int start = offsets[node], end = offsets[node + 1];
  int deg = end - start;

  float ald0 = ald[node];
  int s0 = 0; float wgt0 = 0.f, v0 = 0.f, m0 = -INFINITY;
  if (lane < deg) {
    int e = perm[start + lane];
    s0 = src[e];
    wgt0 = ew[e];
    v0 = leaky02(als[s0] + ald0);
    m0 = v0;
  }
  for (int j = start + 64 + lane; j < end; j += 64) {
    int e = perm[j];
    int s = src[e];
    m0 = fmaxf(m0, leaky02(als[s] + ald0));
  }
  #pragma unroll
  for (int o = 32; o > 0; o >>= 1) m0 = fmaxf(m0, __shfl_xor(m0, o));

  float w0 = (lane < deg) ? __expf(v0 - m0) * wgt0 : 0.f;

  float acc = 0.f, dd = 0.f;
  int cn = deg < 64 ? deg : 64;
  int j = 0;
  for (; j + 8 <= cn; j += 8) {
    float hv[8], wv[8];
    #pragma unroll
    for (int u = 0; u < 8; ++u) {
      int sj = __shfl(s0, j + u);
      wv[u] = __shfl(w0, j + u);
      hv[u] = (float)h16[(size_t)sj * 64 + lane];
    }
    #pragma unroll
    for (int u = 0; u < 8; ++u) { dd += wv[u]; acc += wv[u] * hv[u]; }
  }
  for (; j < cn; ++j) {
    int sj = __shfl(s0, j);
    float wj = __shfl(w0, j);
    dd += wj;
    acc += wj * (float)h16[(size_t)sj * 64 + lane];
  }
  for (int base = start + 64; base < end; base += 64) {
    int cnt = end - base; if (cnt > 64) cnt = 64;
    int st = 0; float u0 = 0.f;
    if (lane < cnt) {
      int e = perm[base + lane];
      st = src[e];
      u0 = __expf(leaky02(als[st] + ald0) - m0) * ew[e];
    }
    for (int jj = 0; jj < cnt; ++jj) {
      int sj = __shfl(st, jj);
      float wj = __shfl(u0, jj);
      dd += wj;
      acc += wj * (float)h16[(size_t)sj * 64 + lane];
    }
  }

  float o = acc / (dd + 1e-16f) + bias[lane];
  if (RELU) o = fmaxf(o, 0.f);
  out[(size_t)node * 64 + lane] = o;
}

// ---------------- launch ----------------

extern "C" void kernel_launch(void* const* d_in, const int* in_sizes, int n_in,
                              void* d_out, int out_size, void* d_ws, size_t ws_size,
                              hipStream_t stream) {
  const int N = NNODES, E = NEDGES;
  const float* x   = (const float*)d_in[0];
  const int*   ei  = (const int*)d_in[1];
  const float* ew  = (const float*)d_in[2];
  const float* W1  = (const float*)d_in[3];
  const float* as1 = (const float*)d_in[4];
  const float* ad1 = (const float*)d_in[5];
  const float* b1  = (const float*)d_in[6];
  const float* W2  = (const float*)d_in[7];
  const float* as2 = (const float*)d_in[8];
  const float* ad2 = (const float*)d_in[9];
  const float* b2  = (const float*)d_in[10];
  const float* W3  = (const float*)d_in[11];
  const float* as3 = (const float*)d_in[12];
  const float* ad3 = (const float*)d_in[13];
  const float* b3  = (const float*)d_in[14];
  const int* src = ei;
  const int* dst = ei + E;

  uint8_t* p = (uint8_t*)d_ws;
  auto carve = [&](size_t bytes) {
    void* r = (void*)p;
    p += (bytes + 255) & ~(size_t)255;
    return r;
  };
  int*   counts  = (int*)carve((size_t)N * 4);
  int*   offsets = (int*)carve((size_t)(N + 1) * 4);
  int*   cursor  = (int*)carve((size_t)N * 4);
  int*   perm    = (int*)carve((size_t)E * 4);
  int*   bsums   = (int*)carve((size_t)256 * 4);
  float* als     = (float*)carve((size_t)N * 4 * 4);
  float* ald     = (float*)carve((size_t)N * 4 * 4);
  f16*   h16     = (f16*)carve((size_t)N * 128 * 2);
  f16*   hB16    = (f16*)carve((size_t)N * 128 * 2);
  f16*   WT1     = (f16*)carve((size_t)256 * 128 * 2);
  f16*   WT2     = (f16*)carve((size_t)128 * 128 * 2);
  f16*   WT3     = (f16*)carve((size_t)128 * 64 * 2);

  // CSR by dst (rebuilt every call) + weight transpose/convert
  int nb = (N + SCAN_CHUNK - 1) / SCAN_CHUNK;
  hipMemsetAsync(counts, 0, (size_t)N * 4, stream);
  hist_kernel<<<(E + 255) / 256, 256, 0, stream>>>(dst, counts, E);
  scan_reduce_kernel<<<nb, 256, 0, stream>>>(counts, bsums, N);
  scan_spine_kernel<<<1, 64, 0, stream>>>(bsums, offsets, nb, N);
  scan_write_kernel<<<nb, 256, 0, stream>>>(counts, bsums, offsets, cursor, N);
  scatter_kernel<<<(E + 255) / 256, 256, 0, stream>>>(dst, cursor, perm, E);
  prepw_kernel<<<224, 256, 0, stream>>>(W1, W2, W3, WT1, WT2, WT3);

  int aggGrid = (N + 3) / 4;
  int gemmGrid = (N + 63) / 64;

  // layer 1: [N,256] @ [256,128], H=4 C=32, relu
  gemm_mfma_kernel<float, 128><<<gemmGrid, 256, 0, stream>>>(x, WT1, h16, N, 256);
  attnlog_kernel<4, 32><<<N, 128, 0, stream>>>(h16, as1, ad1, als, ald, N);
  aggregate4_kernel<true><<<aggGrid, 256, 0, stream>>>(h16, als, ald, ew, src, offsets,
                                                       perm, b1, hB16, N);
  // layer 2: [N,128] @ [128,128], H=4 C=32, relu
  gemm_mfma_kernel<f16, 128><<<gemmGrid, 256, 0, stream>>>(hB16, WT2, h16, N, 128);
  attnlog_kernel<4, 32><<<N, 128, 0, stream>>>(h16, as2, ad2, als, ald, N);
  aggregate4_kernel<true><<<aggGrid, 256, 0, stream>>>(h16, als, ald, ew, src, offsets,
                                                       perm, b2, hB16, N);
  // layer 3: [N,128] @ [128,64], H=1 C=64, no relu, fp32 output
  gemm_mfma_kernel<f16, 64><<<gemmGrid, 256, 0, stream>>>(hB16, WT3, h16, N, 128);
  attnlog_kernel<1, 64><<<N, 64, 0, stream>>>(h16, as3, ad3, als, ald, N);
  aggregate1_kernel<false><<<aggGrid, 256, 0, stream>>>(h16, als, ald, ew, src, offsets,
                                                        perm, b3, (float*)d_out, N);
}